// Round 8
// baseline (677.841 us; speedup 1.0000x reference)
//
#include <hip/hip_runtime.h>
#include <hip/hip_bf16.h>
#include <climits>

// out[csr[i]] += x[ptrs[i]]
//   X_SIZE = 8,388,608 f32 (32 MB), NNZ = 33,554,432, N_SEG = 8,388,608, csr SORTED.
//
// R7 post-mortem: K2 gather = 0.21 gathers/cyc/CU regardless of ILP ->
// per-CU L1-miss (MSHR) throughput wall (~43 lines in flight / ~200cyc L2
// latency). Fix: gathers must HIT, not miss. R8: NB=256 buckets (slice =
// 32768 floats = 128 KiB) staged in LDS; K2 = block-per-bucket, gathers are
// ds_read (no L1/MSHR involvement at all).
//   K1: chunk-local 256-way bin (LDS hist + scan + cursor scatter; unstable,
//       K3 is order-agnostic). Writes per-chunk exclusive offsets (ushort).
//   kT: transpose offs [chunks][256] -> offsT [256][chunks] (coalesced K2 reads).
//   K2: block b: x slice -> LDS (coalesced), thread t walks chunks 4t..4t+3's
//       bucket-b segments: batch-8 ptr loads (L1-reused, thread-sequential),
//       LDS gather, sequential v stores.
//   K3: per-chunk LDS window combine (R3-proven trim: interior segs exclusively
//       owned by csr sortedness -> nt store; first/last seg -> atomicAdd).
// NPASS=2, ws ~196 MB (proven available). Fallback = proven R3 kernel.

#define THREADS 256
#define PER_THREAD 16
#define EPB (THREADS * PER_THREAD)   // 4096 entries per chunk
#define NB 256                       // buckets; slice = 128 KiB
#define SLICE 32768                  // floats per slice (= X_SIZE / NB)
#define NPASS 2
#define K2T 1024                     // K2 block size
#define CPT 4                        // chunks per K2 thread (chunksP / K2T)
#define WIN 8192                     // K3 LDS window (32 KB)
#define LDS_SEGS_FB 4096

typedef int   vint4   __attribute__((ext_vector_type(4)));
typedef float vfloat4 __attribute__((ext_vector_type(4)));

// ---------------------------------------------------------------- K1
// Chunk-local 256-way bin. LDS histogram -> Hillis-Steele scan (256 thr =
// 256 bins) -> atomic-cursor scatter into LDS -> linear coalesced writeout.
__global__ __launch_bounds__(THREADS) void k1_bin256(
    const int* __restrict__ ptrs, const int* __restrict__ csr,
    int* __restrict__ ptrB, int* __restrict__ csrB,
    unsigned short* __restrict__ offs, int shift)
{
    __shared__ int  hist[NB];
    __shared__ int  scanb[NB];
    __shared__ int  curs[NB];
    __shared__ int2 buf[EPB];                 // 32 KB

    const int tid = threadIdx.x;              // THREADS == NB == 256
    const long long cb = (long long)blockIdx.x * EPB;
    const long long base = cb + (long long)tid * PER_THREAD;

    const vint4* p4 = (const vint4*)(ptrs + base);
    const vint4* c4 = (const vint4*)(csr + base);
    int p[PER_THREAD], c[PER_THREAD];
#pragma unroll
    for (int k = 0; k < PER_THREAD / 4; ++k) {
        vint4 a = __builtin_nontemporal_load(p4 + k);
        vint4 b = __builtin_nontemporal_load(c4 + k);
        p[4 * k + 0] = a.x; p[4 * k + 1] = a.y; p[4 * k + 2] = a.z; p[4 * k + 3] = a.w;
        c[4 * k + 0] = b.x; c[4 * k + 1] = b.y; c[4 * k + 2] = b.z; c[4 * k + 3] = b.w;
    }

    hist[tid] = 0;
    __syncthreads();
#pragma unroll
    for (int j = 0; j < PER_THREAD; ++j)
        atomicAdd(&hist[p[j] >> shift], 1);
    __syncthreads();

    const int hv = hist[tid];
    scanb[tid] = hv;
    __syncthreads();
    for (int d = 1; d < NB; d <<= 1) {
        int u = (tid >= d) ? scanb[tid - d] : 0;
        __syncthreads();
        scanb[tid] += u;
        __syncthreads();
    }
    const int excl = scanb[tid] - hv;         // exclusive prefix
    curs[tid] = excl;
    offs[(size_t)blockIdx.x * NB + tid] = (unsigned short)excl;
    __syncthreads();

#pragma unroll
    for (int j = 0; j < PER_THREAD; ++j) {
        const int b = p[j] >> shift;
        const int pos = atomicAdd(&curs[b], 1);
        buf[pos] = make_int2(p[j], c[j]);
    }
    __syncthreads();

    for (int i = tid; i < EPB; i += THREADS) {
        int2 e = buf[i];
        __builtin_nontemporal_store(e.x, ptrB + cb + i);
        __builtin_nontemporal_store(e.y, csrB + cb + i);
    }
}

// ---------------------------------------------------------------- kT
// offs [chunksP][NB] ushort -> offsT [NB][chunksP]. 64x64 LDS tile.
__global__ __launch_bounds__(THREADS) void kT_transpose(
    const unsigned short* __restrict__ in, unsigned short* __restrict__ out,
    int chunksP)
{
    __shared__ unsigned short t[64][65];
    const int c  = threadIdx.x & 63;
    const int r4 = threadIdx.x >> 6;
    const int j0 = blockIdx.x * 64;
    const int b0 = blockIdx.y * 64;
    for (int rr = r4; rr < 64; rr += 4)
        t[rr][c] = in[(size_t)(j0 + rr) * NB + b0 + c];
    __syncthreads();
    for (int rr = r4; rr < 64; rr += 4)
        out[(size_t)(b0 + rr) * chunksP + j0 + c] = t[c][rr];
}

// ---------------------------------------------------------------- K2
// Block b: stage x slice b (128 KiB) in LDS, then gather all of bucket b's
// entries (every chunk) from LDS. ptr loads are thread-sequential (L1/L2
// reuse, keep cached); 8-deep batches for MLP on the ptr stream.
__global__ __launch_bounds__(K2T) void k2_ldsgather(
    const float* __restrict__ x, const int* __restrict__ ptrB,
    const unsigned short* __restrict__ offsT, float* __restrict__ v,
    int chunksP)
{
    __shared__ float sl[SLICE];               // 128 KiB
    const int tid = threadIdx.x;
    const int b = blockIdx.x;

    const vfloat4* xs = (const vfloat4*)(x + (size_t)b * SLICE);
    vfloat4* ls = (vfloat4*)sl;
    for (int i = tid; i < SLICE / 4; i += K2T)
        ls[i] = xs[i];
    __syncthreads();

    const unsigned short* rowS = offsT + (size_t)b * chunksP;
    const unsigned short* rowE = offsT + (size_t)(b + 1) * chunksP;  // not deref'd for b==NB-1
    const bool last = (b == NB - 1);

#pragma unroll
    for (int cj = 0; cj < CPT; ++cj) {
        const int jj = tid * CPT + cj;
        const long long cbk = (long long)jj * EPB;
        const int s = rowS[jj];
        const int e = last ? EPB : (int)rowE[jj];
        for (int i = s; i < e; i += 8) {
            const int n = e - i;
            int pi[8];
#pragma unroll
            for (int k = 0; k < 8; ++k) {
                const int kk = (k < n) ? k : (n - 1);
                pi[k] = ptrB[cbk + i + kk];   // cached: line reused by this thread
            }
            float vv[8];
#pragma unroll
            for (int k = 0; k < 8; ++k)
                vv[k] = sl[pi[k] & (SLICE - 1)];   // LDS gather: no L1/MSHR
#pragma unroll
            for (int k = 0; k < 8; ++k)
                if (k < n) v[cbk + i + k] = vv[k];
        }
    }
}

// ---------------------------------------------------------------- K3
// Block per chunk: dense LDS window over the chunk's segment span; interior
// segs exclusively owned (csr sorted) -> nt store; first/last seg atomic.
// Order-agnostic (csrB is scrambled within chunk).
__global__ __launch_bounds__(THREADS) void k3_combine(
    const int* __restrict__ csrOrig, const int* __restrict__ csrB,
    const float* __restrict__ v, float* __restrict__ out)
{
    __shared__ float win[WIN];
    __shared__ int s_sb, s_sl;

    const int tid = threadIdx.x;
    const long long cb = (long long)blockIdx.x * EPB;

    if (tid == 0) { s_sb = csrOrig[cb]; s_sl = csrOrig[cb + EPB - 1]; }

    const vint4*   c4 = (const vint4*)(csrB + cb + (long long)tid * PER_THREAD);
    const vfloat4* v4 = (const vfloat4*)(v + cb + (long long)tid * PER_THREAD);
    int cc[PER_THREAD]; float vv[PER_THREAD];
#pragma unroll
    for (int k = 0; k < PER_THREAD / 4; ++k) {
        vint4   a = __builtin_nontemporal_load(c4 + k);
        vfloat4 f = __builtin_nontemporal_load(v4 + k);
        cc[4 * k + 0] = a.x; cc[4 * k + 1] = a.y; cc[4 * k + 2] = a.z; cc[4 * k + 3] = a.w;
        vv[4 * k + 0] = f.x; vv[4 * k + 1] = f.y; vv[4 * k + 2] = f.z; vv[4 * k + 3] = f.w;
    }
    __syncthreads();
    const int sb = s_sb, sl = s_sl;

    for (int wb = sb; wb <= sl; wb += WIN) {
        const int we = (wb + WIN - 1 < sl) ? (wb + WIN - 1) : sl;
        const int wlen = we - wb + 1;
        for (int s = tid; s < wlen; s += THREADS) win[s] = 0.0f;
        __syncthreads();

        float acc = vv[0]; int cur = cc[0];
#pragma unroll
        for (int j = 1; j < PER_THREAD; ++j) {
            if (cc[j] == cur) acc += vv[j];
            else {
                if (cur >= wb && cur <= we) atomicAdd(&win[cur - wb], acc);
                cur = cc[j]; acc = vv[j];
            }
        }
        if (cur >= wb && cur <= we) atomicAdd(&win[cur - wb], acc);
        __syncthreads();

        for (int s = tid; s < wlen; s += THREADS) {
            const int g = wb + s;
            const float val = win[s];
            if (g == sb || g == sl) { if (val != 0.0f) atomicAdd(out + g, val); }
            else __builtin_nontemporal_store(val, out + g);
        }
        __syncthreads();
    }
}

// ------------------------------------------------- Fallback (= proven R3)
__global__ __launch_bounds__(THREADS) void fallback_segsum(
    const float* __restrict__ x, const int* __restrict__ ptrs,
    const int* __restrict__ csr, float* __restrict__ out)
{
    __shared__ float seg[LDS_SEGS_FB];
    const int tid = threadIdx.x;
    const long long blk_base = (long long)blockIdx.x * EPB;
    const long long base = blk_base + (long long)tid * PER_THREAD;

    const int seg_base = csr[blk_base];
    const int seg_last = csr[blk_base + EPB - 1];
    const int span = seg_last - seg_base + 1;

    for (int s = tid; s < LDS_SEGS_FB; s += THREADS) seg[s] = 0.0f;

    const vint4* p4 = (const vint4*)(ptrs + base);
    const vint4* c4 = (const vint4*)(csr + base);
    int p[PER_THREAD], c[PER_THREAD];
#pragma unroll
    for (int k = 0; k < PER_THREAD / 4; ++k) {
        vint4 a = __builtin_nontemporal_load(p4 + k);
        vint4 b = __builtin_nontemporal_load(c4 + k);
        p[4 * k + 0] = a.x; p[4 * k + 1] = a.y; p[4 * k + 2] = a.z; p[4 * k + 3] = a.w;
        c[4 * k + 0] = b.x; c[4 * k + 1] = b.y; c[4 * k + 2] = b.z; c[4 * k + 3] = b.w;
    }
    float v[PER_THREAD];
#pragma unroll
    for (int j = 0; j < PER_THREAD; ++j) v[j] = x[p[j]];
    __syncthreads();

    if (span <= LDS_SEGS_FB) {
        float acc = v[0]; int cur = c[0];
#pragma unroll
        for (int j = 1; j < PER_THREAD; ++j) {
            if (c[j] == cur) acc += v[j];
            else { atomicAdd(&seg[cur - seg_base], acc); cur = c[j]; acc = v[j]; }
        }
        atomicAdd(&seg[cur - seg_base], acc);
        __syncthreads();
        for (int s = tid; s < span; s += THREADS) {
            const int g = seg_base + s;
            const float val = seg[s];
            if (s == 0 || g == seg_last) { if (val != 0.0f) atomicAdd(out + g, val); }
            else __builtin_nontemporal_store(val, out + g);
        }
    } else {
        float acc = v[0]; int cur = c[0];
#pragma unroll
        for (int j = 1; j < PER_THREAD; ++j) {
            if (c[j] == cur) acc += v[j];
            else { atomicAdd(out + cur, acc); cur = c[j]; acc = v[j]; }
        }
        atomicAdd(out + cur, acc);
    }
}

extern "C" void kernel_launch(void* const* d_in, const int* in_sizes, int n_in,
                              void* d_out, int out_size, void* d_ws, size_t ws_size,
                              hipStream_t stream) {
    const float* x    = (const float*)d_in[0];
    const int*   ptrs = (const int*)d_in[1];
    const int*   csr  = (const int*)d_in[2];
    float*       out  = (float*)d_out;

    const long long nnz = in_sizes[1];            // 33,554,432
    const int x_size = in_sizes[0];               // 8,388,608

    (void)hipMemsetAsync(d_out, 0, (size_t)out_size * sizeof(float), stream);

    const long long nnzP = nnz / NPASS;           // 16,777,216
    const long long chunksP = nnzP / EPB;         // 4,096
    const bool ok_shapes =
        (nnz % ((long long)NPASS * EPB) == 0) &&
        (x_size % NB == 0) && (x_size / NB == SLICE) &&
        (chunksP == (long long)K2T * CPT) &&      // K2 thread->chunk mapping
        (chunksP % 64 == 0) &&                    // transpose tiling
        nnzP < (long long)INT_MAX / 2;

    const size_t arrBytes  = ((size_t)nnzP * 4 + 255) & ~(size_t)255;       // x3
    const size_t offsBytes = ((size_t)chunksP * NB * 2 + 255) & ~(size_t)255; // x2
    const size_t need      = 3 * arrBytes + 2 * offsBytes + 512;            // ~196 MB

    if (ok_shapes && ws_size >= need) {
        char* w = (char*)d_ws;
        int*            ptrB  = (int*)w;
        int*            csrB  = (int*)(w + arrBytes);
        float*          vbuf  = (float*)(w + 2 * arrBytes);
        unsigned short* offs  = (unsigned short*)(w + 3 * arrBytes);
        unsigned short* offsT = (unsigned short*)(w + 3 * arrBytes + offsBytes);
        const int shift = __builtin_ctz((unsigned)SLICE);   // 15

        for (int g = 0; g < NPASS; ++g) {
            const int* pg = ptrs + (long long)g * nnzP;
            const int* cg = csr  + (long long)g * nnzP;
            k1_bin256   <<<(int)chunksP, THREADS, 0, stream>>>(pg, cg, ptrB, csrB, offs, shift);
            kT_transpose<<<dim3((int)(chunksP / 64), NB / 64), THREADS, 0, stream>>>(offs, offsT, (int)chunksP);
            k2_ldsgather<<<NB, K2T, 0, stream>>>(x, ptrB, offsT, vbuf, (int)chunksP);
            k3_combine  <<<(int)chunksP, THREADS, 0, stream>>>(cg, csrB, vbuf, out);
        }
    } else {
        fallback_segsum<<<(int)(nnz / EPB), THREADS, 0, stream>>>(x, ptrs, csr, out);
    }
}

// Round 9
// 610.317 us; speedup vs baseline: 1.1106x; 1.1106x over previous
//
#include <hip/hip_runtime.h>
#include <hip/hip_bf16.h>
#include <climits>

// out[csr[i]] += x[ptrs[i]]
//   X_SIZE = 8,388,608 f32 (32 MB), NNZ = 33,554,432, N_SEG = 8,388,608, csr SORTED.
//
// R8 post-mortem: LDS-gather was right; per-THREAD chunk walking was wrong
// (per-lane private lines -> ptrB/v MSHR wall, FETCH 187MB, occ 34%).
// R9: K2 iterates the FLATTENED bucket stream: LDS prefix table over the
// 4096 run lengths; thread t owns 8 consecutive flat entries; a wave covers
// 512 consecutive entries -> coalesced ptrB loads + v stores; gathers from
// the LDS-resident 128KiB x-slice (no L1/MSHR). K1/kT/K3 unchanged (proven).

#define THREADS 256
#define PER_THREAD 16
#define EPB (THREADS * PER_THREAD)   // 4096 entries per chunk
#define NB 256                       // buckets; slice = 128 KiB
#define SLICE 32768                  // floats per slice (= X_SIZE / NB)
#define NPASS 2
#define K2T 1024                     // K2 block size
#define K2U 8                        // flat entries per thread per tile
#define NCH 4096                     // chunks per pass (guarded)
#define WIN 8192                     // K3 LDS window (32 KB)
#define LDS_SEGS_FB 4096

typedef int   vint4   __attribute__((ext_vector_type(4)));
typedef float vfloat4 __attribute__((ext_vector_type(4)));

// ---------------------------------------------------------------- K1
// Chunk-local 256-way bin (unchanged from R8, proven).
__global__ __launch_bounds__(THREADS) void k1_bin256(
    const int* __restrict__ ptrs, const int* __restrict__ csr,
    int* __restrict__ ptrB, int* __restrict__ csrB,
    unsigned short* __restrict__ offs, int shift)
{
    __shared__ int  hist[NB];
    __shared__ int  scanb[NB];
    __shared__ int  curs[NB];
    __shared__ int2 buf[EPB];                 // 32 KB

    const int tid = threadIdx.x;              // THREADS == NB == 256
    const long long cb = (long long)blockIdx.x * EPB;
    const long long base = cb + (long long)tid * PER_THREAD;

    const vint4* p4 = (const vint4*)(ptrs + base);
    const vint4* c4 = (const vint4*)(csr + base);
    int p[PER_THREAD], c[PER_THREAD];
#pragma unroll
    for (int k = 0; k < PER_THREAD / 4; ++k) {
        vint4 a = __builtin_nontemporal_load(p4 + k);
        vint4 b = __builtin_nontemporal_load(c4 + k);
        p[4 * k + 0] = a.x; p[4 * k + 1] = a.y; p[4 * k + 2] = a.z; p[4 * k + 3] = a.w;
        c[4 * k + 0] = b.x; c[4 * k + 1] = b.y; c[4 * k + 2] = b.z; c[4 * k + 3] = b.w;
    }

    hist[tid] = 0;
    __syncthreads();
#pragma unroll
    for (int j = 0; j < PER_THREAD; ++j)
        atomicAdd(&hist[p[j] >> shift], 1);
    __syncthreads();

    const int hv = hist[tid];
    scanb[tid] = hv;
    __syncthreads();
    for (int d = 1; d < NB; d <<= 1) {
        int u = (tid >= d) ? scanb[tid - d] : 0;
        __syncthreads();
        scanb[tid] += u;
        __syncthreads();
    }
    const int excl = scanb[tid] - hv;         // exclusive prefix
    curs[tid] = excl;
    offs[(size_t)blockIdx.x * NB + tid] = (unsigned short)excl;
    __syncthreads();

#pragma unroll
    for (int j = 0; j < PER_THREAD; ++j) {
        const int b = p[j] >> shift;
        const int pos = atomicAdd(&curs[b], 1);
        buf[pos] = make_int2(p[j], c[j]);
    }
    __syncthreads();

    for (int i = tid; i < EPB; i += THREADS) {
        int2 e = buf[i];
        __builtin_nontemporal_store(e.x, ptrB + cb + i);
        __builtin_nontemporal_store(e.y, csrB + cb + i);
    }
}

// ---------------------------------------------------------------- kT
// offs [chunksP][NB] ushort -> offsT [NB][chunksP] (unchanged, proven).
__global__ __launch_bounds__(THREADS) void kT_transpose(
    const unsigned short* __restrict__ in, unsigned short* __restrict__ out,
    int chunksP)
{
    __shared__ unsigned short t[64][65];
    const int c  = threadIdx.x & 63;
    const int r4 = threadIdx.x >> 6;
    const int j0 = blockIdx.x * 64;
    const int b0 = blockIdx.y * 64;
    for (int rr = r4; rr < 64; rr += 4)
        t[rr][c] = in[(size_t)(j0 + rr) * NB + b0 + c];
    __syncthreads();
    for (int rr = r4; rr < 64; rr += 4)
        out[(size_t)(b0 + rr) * chunksP + j0 + c] = t[c][rr];
}

// ---------------------------------------------------------------- K2
// Block b: stage x slice b (128 KiB) in LDS; build LDS prefix over the 4096
// run lengths; iterate the FLAT bucket stream with 8 consecutive entries per
// thread (wave = 512 consecutive -> coalesced ptrB/v). Gather = ds_read.
__global__ __launch_bounds__(K2T) void k2_ldsgather(
    const float* __restrict__ x, const int* __restrict__ ptrB,
    const unsigned short* __restrict__ offsT, float* __restrict__ v,
    int chunksP)
{
    __shared__ float sl[SLICE];               // 128 KiB
    __shared__ int   pfx[NCH];                // 16 KiB (runLen, then excl prefix)
    __shared__ int   scanTmp[K2T];            // 4 KiB
    __shared__ int   sTot;

    const int tid = threadIdx.x;
    const int b = blockIdx.x;
    const bool lastB = (b == NB - 1);

    // stage slice (nontemporal: read exactly once per pass)
    const vfloat4* xs = (const vfloat4*)(x + (size_t)b * SLICE);
    vfloat4* ls = (vfloat4*)sl;
    for (int i = tid; i < SLICE / 4; i += K2T)
        ls[i] = __builtin_nontemporal_load(xs + i);

    // run lengths for this bucket across all chunks
    const unsigned short* rowS = offsT + (size_t)b * chunksP;
    const unsigned short* rowE = offsT + (size_t)(b + 1) * chunksP;
    for (int j = tid; j < NCH; j += K2T) {
        const int s = rowS[j];
        const int e = lastB ? EPB : (int)rowE[j];
        pfx[j] = e - s;
    }
    __syncthreads();

    // block scan: 4 runs per thread -> 1024-wide Hillis-Steele -> write back
    const int bse = tid * 4;
    const int l0 = pfx[bse], l1 = pfx[bse + 1], l2 = pfx[bse + 2], l3 = pfx[bse + 3];
    const int lsum = l0 + l1 + l2 + l3;
    scanTmp[tid] = lsum;
    __syncthreads();
    for (int d = 1; d < K2T; d <<= 1) {
        int u = (tid >= d) ? scanTmp[tid - d] : 0;
        __syncthreads();
        scanTmp[tid] += u;
        __syncthreads();
    }
    const int texcl = scanTmp[tid] - lsum;
    pfx[bse]     = texcl;
    pfx[bse + 1] = texcl + l0;
    pfx[bse + 2] = texcl + l0 + l1;
    pfx[bse + 3] = texcl + l0 + l1 + l2;
    if (tid == K2T - 1) sTot = texcl + lsum;
    __syncthreads();
    const int T = sTot;

    for (int fb = 0; fb < T; fb += K2T * K2U) {
        const int f0 = fb + tid * K2U;

        // binary search: largest j with pfx[j] <= f0
        int j = 0;
#pragma unroll
        for (int s = NCH / 2; s > 0; s >>= 1) {
            const int m = j + s;
            if (m < NCH && pfx[m] <= f0) j = m;
        }

        // resolve 8 consecutive flat entries (advance j across runs)
        long long gi[K2U];
        int jj = j;
#pragma unroll
        for (int k = 0; k < K2U; ++k) {
            const int f = f0 + k;
            if (f < T) {
                while (jj + 1 < NCH && pfx[jj + 1] <= f) ++jj;
                gi[k] = (long long)jj * EPB + (int)rowS[jj] + (f - pfx[jj]);
            } else gi[k] = -1;
        }
        // batch ptr loads (coalesced across wave; L1 reuse within thread)
        int pi[K2U];
#pragma unroll
        for (int k = 0; k < K2U; ++k)
            pi[k] = (gi[k] >= 0) ? ptrB[gi[k]] : 0;
        // LDS gathers
        float va[K2U];
#pragma unroll
        for (int k = 0; k < K2U; ++k)
            va[k] = sl[pi[k] & (SLICE - 1)];
        // batch stores (coalesced)
#pragma unroll
        for (int k = 0; k < K2U; ++k)
            if (gi[k] >= 0) v[gi[k]] = va[k];
    }
}

// ---------------------------------------------------------------- K3
// Block per chunk: dense LDS window; interior segs exclusively owned (csr
// sorted) -> nt store; first/last seg atomic. Order-agnostic (unchanged).
__global__ __launch_bounds__(THREADS) void k3_combine(
    const int* __restrict__ csrOrig, const int* __restrict__ csrB,
    const float* __restrict__ v, float* __restrict__ out)
{
    __shared__ float win[WIN];
    __shared__ int s_sb, s_sl;

    const int tid = threadIdx.x;
    const long long cb = (long long)blockIdx.x * EPB;

    if (tid == 0) { s_sb = csrOrig[cb]; s_sl = csrOrig[cb + EPB - 1]; }

    const vint4*   c4 = (const vint4*)(csrB + cb + (long long)tid * PER_THREAD);
    const vfloat4* v4 = (const vfloat4*)(v + cb + (long long)tid * PER_THREAD);
    int cc[PER_THREAD]; float vv[PER_THREAD];
#pragma unroll
    for (int k = 0; k < PER_THREAD / 4; ++k) {
        vint4   a = __builtin_nontemporal_load(c4 + k);
        vfloat4 f = __builtin_nontemporal_load(v4 + k);
        cc[4 * k + 0] = a.x; cc[4 * k + 1] = a.y; cc[4 * k + 2] = a.z; cc[4 * k + 3] = a.w;
        vv[4 * k + 0] = f.x; vv[4 * k + 1] = f.y; vv[4 * k + 2] = f.z; vv[4 * k + 3] = f.w;
    }
    __syncthreads();
    const int sb = s_sb, sl = s_sl;

    for (int wb = sb; wb <= sl; wb += WIN) {
        const int we = (wb + WIN - 1 < sl) ? (wb + WIN - 1) : sl;
        const int wlen = we - wb + 1;
        for (int s = tid; s < wlen; s += THREADS) win[s] = 0.0f;
        __syncthreads();

        float acc = vv[0]; int cur = cc[0];
#pragma unroll
        for (int j = 1; j < PER_THREAD; ++j) {
            if (cc[j] == cur) acc += vv[j];
            else {
                if (cur >= wb && cur <= we) atomicAdd(&win[cur - wb], acc);
                cur = cc[j]; acc = vv[j];
            }
        }
        if (cur >= wb && cur <= we) atomicAdd(&win[cur - wb], acc);
        __syncthreads();

        for (int s = tid; s < wlen; s += THREADS) {
            const int g = wb + s;
            const float val = win[s];
            if (g == sb || g == sl) { if (val != 0.0f) atomicAdd(out + g, val); }
            else __builtin_nontemporal_store(val, out + g);
        }
        __syncthreads();
    }
}

// ------------------------------------------------- Fallback (= proven R3)
__global__ __launch_bounds__(THREADS) void fallback_segsum(
    const float* __restrict__ x, const int* __restrict__ ptrs,
    const int* __restrict__ csr, float* __restrict__ out)
{
    __shared__ float seg[LDS_SEGS_FB];
    const int tid = threadIdx.x;
    const long long blk_base = (long long)blockIdx.x * EPB;
    const long long base = blk_base + (long long)tid * PER_THREAD;

    const int seg_base = csr[blk_base];
    const int seg_last = csr[blk_base + EPB - 1];
    const int span = seg_last - seg_base + 1;

    for (int s = tid; s < LDS_SEGS_FB; s += THREADS) seg[s] = 0.0f;

    const vint4* p4 = (const vint4*)(ptrs + base);
    const vint4* c4 = (const vint4*)(csr + base);
    int p[PER_THREAD], c[PER_THREAD];
#pragma unroll
    for (int k = 0; k < PER_THREAD / 4; ++k) {
        vint4 a = __builtin_nontemporal_load(p4 + k);
        vint4 b = __builtin_nontemporal_load(c4 + k);
        p[4 * k + 0] = a.x; p[4 * k + 1] = a.y; p[4 * k + 2] = a.z; p[4 * k + 3] = a.w;
        c[4 * k + 0] = b.x; c[4 * k + 1] = b.y; c[4 * k + 2] = b.z; c[4 * k + 3] = b.w;
    }
    float v[PER_THREAD];
#pragma unroll
    for (int j = 0; j < PER_THREAD; ++j) v[j] = x[p[j]];
    __syncthreads();

    if (span <= LDS_SEGS_FB) {
        float acc = v[0]; int cur = c[0];
#pragma unroll
        for (int j = 1; j < PER_THREAD; ++j) {
            if (c[j] == cur) acc += v[j];
            else { atomicAdd(&seg[cur - seg_base], acc); cur = c[j]; acc = v[j]; }
        }
        atomicAdd(&seg[cur - seg_base], acc);
        __syncthreads();
        for (int s = tid; s < span; s += THREADS) {
            const int g = seg_base + s;
            const float val = seg[s];
            if (s == 0 || g == seg_last) { if (val != 0.0f) atomicAdd(out + g, val); }
            else __builtin_nontemporal_store(val, out + g);
        }
    } else {
        float acc = v[0]; int cur = c[0];
#pragma unroll
        for (int j = 1; j < PER_THREAD; ++j) {
            if (c[j] == cur) acc += v[j];
            else { atomicAdd(out + cur, acc); cur = c[j]; acc = v[j]; }
        }
        atomicAdd(out + cur, acc);
    }
}

extern "C" void kernel_launch(void* const* d_in, const int* in_sizes, int n_in,
                              void* d_out, int out_size, void* d_ws, size_t ws_size,
                              hipStream_t stream) {
    const float* x    = (const float*)d_in[0];
    const int*   ptrs = (const int*)d_in[1];
    const int*   csr  = (const int*)d_in[2];
    float*       out  = (float*)d_out;

    const long long nnz = in_sizes[1];            // 33,554,432
    const int x_size = in_sizes[0];               // 8,388,608

    (void)hipMemsetAsync(d_out, 0, (size_t)out_size * sizeof(float), stream);

    const long long nnzP = nnz / NPASS;           // 16,777,216
    const long long chunksP = nnzP / EPB;         // 4,096
    const bool ok_shapes =
        (nnz % ((long long)NPASS * EPB) == 0) &&
        (x_size % NB == 0) && (x_size / NB == SLICE) &&
        (chunksP == NCH) &&                        // K2 prefix table sizing
        (chunksP % 64 == 0) &&                     // transpose tiling
        nnzP < (long long)INT_MAX / 2;

    const size_t arrBytes  = ((size_t)nnzP * 4 + 255) & ~(size_t)255;       // x3
    const size_t offsBytes = ((size_t)chunksP * NB * 2 + 255) & ~(size_t)255; // x2
    const size_t need      = 3 * arrBytes + 2 * offsBytes + 512;            // ~196 MB

    if (ok_shapes && ws_size >= need) {
        char* w = (char*)d_ws;
        int*            ptrB  = (int*)w;
        int*            csrB  = (int*)(w + arrBytes);
        float*          vbuf  = (float*)(w + 2 * arrBytes);
        unsigned short* offs  = (unsigned short*)(w + 3 * arrBytes);
        unsigned short* offsT = (unsigned short*)(w + 3 * arrBytes + offsBytes);
        const int shift = __builtin_ctz((unsigned)SLICE);   // 15

        for (int g = 0; g < NPASS; ++g) {
            const int* pg = ptrs + (long long)g * nnzP;
            const int* cg = csr  + (long long)g * nnzP;
            k1_bin256   <<<(int)chunksP, THREADS, 0, stream>>>(pg, cg, ptrB, csrB, offs, shift);
            kT_transpose<<<dim3((int)(chunksP / 64), NB / 64), THREADS, 0, stream>>>(offs, offsT, (int)chunksP);
            k2_ldsgather<<<NB, K2T, 0, stream>>>(x, ptrB, offsT, vbuf, (int)chunksP);
            k3_combine  <<<(int)chunksP, THREADS, 0, stream>>>(cg, csrB, vbuf, out);
        }
    } else {
        fallback_segsum<<<(int)(nnz / EPB), THREADS, 0, stream>>>(x, ptrs, csr, out);
    }
}

// Round 10
// 512.942 us; speedup vs baseline: 1.3215x; 1.1898x over previous
//
#include <hip/hip_runtime.h>
#include <hip/hip_bf16.h>
#include <climits>

// out[csr[i]] += x[ptrs[i]]
//   X_SIZE = 8,388,608 f32 (32 MB), NNZ = 33,554,432, N_SEG = 8,388,608, csr SORTED.
//
// R9 post-mortem: K2's thread-major flat assignment (thread owns 8 CONSECUTIVE
// flats) made each wave-instr touch ~48 lines (32 runs x different chunks) ->
// L1 miss-slot wall again (0.18 ent/cyc/CU, FETCH ideal). R10: lane-major
// assignment f = fb + k*K2T + tid -> wave-instr covers 64 consecutive flats
// (~5 lines); per-k independent binary searches in LDS prefix (ILP-hidden,
// broadcast-heavy). K1/kT/K3 unchanged.

#define THREADS 256
#define PER_THREAD 16
#define EPB (THREADS * PER_THREAD)   // 4096 entries per chunk
#define NB 256                       // buckets; slice = 128 KiB
#define SLICE 32768                  // floats per slice (= X_SIZE / NB)
#define NPASS 2
#define K2T 1024                     // K2 block size
#define K2U 8                        // flat entries per thread per tile
#define NCH 4096                     // chunks per pass (guarded)
#define WIN 8192                     // K3 LDS window (32 KB)
#define LDS_SEGS_FB 4096

typedef int   vint4   __attribute__((ext_vector_type(4)));
typedef float vfloat4 __attribute__((ext_vector_type(4)));

// ---------------------------------------------------------------- K1
// Chunk-local 256-way bin (unchanged, proven).
__global__ __launch_bounds__(THREADS) void k1_bin256(
    const int* __restrict__ ptrs, const int* __restrict__ csr,
    int* __restrict__ ptrB, int* __restrict__ csrB,
    unsigned short* __restrict__ offs, int shift)
{
    __shared__ int  hist[NB];
    __shared__ int  scanb[NB];
    __shared__ int  curs[NB];
    __shared__ int2 buf[EPB];                 // 32 KB

    const int tid = threadIdx.x;              // THREADS == NB == 256
    const long long cb = (long long)blockIdx.x * EPB;
    const long long base = cb + (long long)tid * PER_THREAD;

    const vint4* p4 = (const vint4*)(ptrs + base);
    const vint4* c4 = (const vint4*)(csr + base);
    int p[PER_THREAD], c[PER_THREAD];
#pragma unroll
    for (int k = 0; k < PER_THREAD / 4; ++k) {
        vint4 a = __builtin_nontemporal_load(p4 + k);
        vint4 b = __builtin_nontemporal_load(c4 + k);
        p[4 * k + 0] = a.x; p[4 * k + 1] = a.y; p[4 * k + 2] = a.z; p[4 * k + 3] = a.w;
        c[4 * k + 0] = b.x; c[4 * k + 1] = b.y; c[4 * k + 2] = b.z; c[4 * k + 3] = b.w;
    }

    hist[tid] = 0;
    __syncthreads();
#pragma unroll
    for (int j = 0; j < PER_THREAD; ++j)
        atomicAdd(&hist[p[j] >> shift], 1);
    __syncthreads();

    const int hv = hist[tid];
    scanb[tid] = hv;
    __syncthreads();
    for (int d = 1; d < NB; d <<= 1) {
        int u = (tid >= d) ? scanb[tid - d] : 0;
        __syncthreads();
        scanb[tid] += u;
        __syncthreads();
    }
    const int excl = scanb[tid] - hv;         // exclusive prefix
    curs[tid] = excl;
    offs[(size_t)blockIdx.x * NB + tid] = (unsigned short)excl;
    __syncthreads();

#pragma unroll
    for (int j = 0; j < PER_THREAD; ++j) {
        const int b = p[j] >> shift;
        const int pos = atomicAdd(&curs[b], 1);
        buf[pos] = make_int2(p[j], c[j]);
    }
    __syncthreads();

    for (int i = tid; i < EPB; i += THREADS) {
        int2 e = buf[i];
        __builtin_nontemporal_store(e.x, ptrB + cb + i);
        __builtin_nontemporal_store(e.y, csrB + cb + i);
    }
}

// ---------------------------------------------------------------- kT
// offs [chunksP][NB] ushort -> offsT [NB][chunksP] (unchanged, proven).
__global__ __launch_bounds__(THREADS) void kT_transpose(
    const unsigned short* __restrict__ in, unsigned short* __restrict__ out,
    int chunksP)
{
    __shared__ unsigned short t[64][65];
    const int c  = threadIdx.x & 63;
    const int r4 = threadIdx.x >> 6;
    const int j0 = blockIdx.x * 64;
    const int b0 = blockIdx.y * 64;
    for (int rr = r4; rr < 64; rr += 4)
        t[rr][c] = in[(size_t)(j0 + rr) * NB + b0 + c];
    __syncthreads();
    for (int rr = r4; rr < 64; rr += 4)
        out[(size_t)(b0 + rr) * chunksP + j0 + c] = t[c][rr];
}

// ---------------------------------------------------------------- K2
// Block b: stage x slice b (128 KiB) + run-start table + prefix table in LDS.
// Lane-major flat iteration: per k, a wave covers 64 CONSECUTIVE flat entries
// (~5 lines on ptrB/v). 8 independent binary searches per thread per tile
// (ILP-hidden, broadcast-heavy LDS reads). Gather = ds_read, no L1/MSHR.
__global__ __launch_bounds__(K2T) void k2_ldsgather(
    const float* __restrict__ x, const int* __restrict__ ptrB,
    const unsigned short* __restrict__ offsT, float* __restrict__ v,
    int chunksP)
{
    __shared__ float          sl[SLICE];      // 128 KiB
    __shared__ int            pfx[NCH];       // 16 KiB (excl prefix of run lens)
    __shared__ unsigned short srs[NCH];       // 8 KiB (run starts within chunk)
    __shared__ int            scanTmp[K2T];   // 4 KiB
    __shared__ int            sTot;

    const int tid = threadIdx.x;
    const int b = blockIdx.x;
    const bool lastB = (b == NB - 1);

    // stage slice (read exactly once per pass)
    const vfloat4* xs = (const vfloat4*)(x + (size_t)b * SLICE);
    vfloat4* ls = (vfloat4*)sl;
    for (int i = tid; i < SLICE / 4; i += K2T)
        ls[i] = __builtin_nontemporal_load(xs + i);

    // run starts + lengths for this bucket across all chunks
    const unsigned short* rowS = offsT + (size_t)b * chunksP;
    const unsigned short* rowE = offsT + (size_t)(b + 1) * chunksP;
    for (int j = tid; j < NCH; j += K2T) {
        const int s = rowS[j];
        const int e = lastB ? EPB : (int)rowE[j];
        srs[j] = (unsigned short)s;
        pfx[j] = e - s;
    }
    __syncthreads();

    // block scan of run lengths: 4 per thread -> 1024-wide Hillis-Steele
    const int bse = tid * 4;
    const int l0 = pfx[bse], l1 = pfx[bse + 1], l2 = pfx[bse + 2], l3 = pfx[bse + 3];
    const int lsum = l0 + l1 + l2 + l3;
    scanTmp[tid] = lsum;
    __syncthreads();
    for (int d = 1; d < K2T; d <<= 1) {
        int u = (tid >= d) ? scanTmp[tid - d] : 0;
        __syncthreads();
        scanTmp[tid] += u;
        __syncthreads();
    }
    const int texcl = scanTmp[tid] - lsum;
    pfx[bse]     = texcl;
    pfx[bse + 1] = texcl + l0;
    pfx[bse + 2] = texcl + l0 + l1;
    pfx[bse + 3] = texcl + l0 + l1 + l2;
    if (tid == K2T - 1) sTot = texcl + lsum;
    __syncthreads();
    const int T = sTot;

    for (int fb = 0; fb < T; fb += K2T * K2U) {
        // 8 independent run lookups (lane-major: wave = 64 consecutive flats)
        int gi[K2U];
#pragma unroll
        for (int k = 0; k < K2U; ++k) {
            const int f = fb + k * K2T + tid;
            if (f < T) {
                int j = 0;
#pragma unroll
                for (int s = NCH / 2; s > 0; s >>= 1)
                    if (j + s < NCH && pfx[j + s] <= f) j += s;
                gi[k] = j * EPB + (int)srs[j] + (f - pfx[j]);
            } else gi[k] = -1;
        }
        // batch ptr loads (~5 lines per wave-instr)
        int pi[K2U];
#pragma unroll
        for (int k = 0; k < K2U; ++k)
            pi[k] = (gi[k] >= 0) ? ptrB[gi[k]] : 0;
        // LDS gathers
        float va[K2U];
#pragma unroll
        for (int k = 0; k < K2U; ++k)
            va[k] = sl[pi[k] & (SLICE - 1)];
        // batch stores (~5 lines per wave-instr)
#pragma unroll
        for (int k = 0; k < K2U; ++k)
            if (gi[k] >= 0) v[gi[k]] = va[k];
    }
}

// ---------------------------------------------------------------- K3
// Block per chunk: dense LDS window; interior segs exclusively owned (csr
// sorted) -> nt store; first/last seg atomic. Order-agnostic (unchanged).
__global__ __launch_bounds__(THREADS) void k3_combine(
    const int* __restrict__ csrOrig, const int* __restrict__ csrB,
    const float* __restrict__ v, float* __restrict__ out)
{
    __shared__ float win[WIN];
    __shared__ int s_sb, s_sl;

    const int tid = threadIdx.x;
    const long long cb = (long long)blockIdx.x * EPB;

    if (tid == 0) { s_sb = csrOrig[cb]; s_sl = csrOrig[cb + EPB - 1]; }

    const vint4*   c4 = (const vint4*)(csrB + cb + (long long)tid * PER_THREAD);
    const vfloat4* v4 = (const vfloat4*)(v + cb + (long long)tid * PER_THREAD);
    int cc[PER_THREAD]; float vv[PER_THREAD];
#pragma unroll
    for (int k = 0; k < PER_THREAD / 4; ++k) {
        vint4   a = __builtin_nontemporal_load(c4 + k);
        vfloat4 f = __builtin_nontemporal_load(v4 + k);
        cc[4 * k + 0] = a.x; cc[4 * k + 1] = a.y; cc[4 * k + 2] = a.z; cc[4 * k + 3] = a.w;
        vv[4 * k + 0] = f.x; vv[4 * k + 1] = f.y; vv[4 * k + 2] = f.z; vv[4 * k + 3] = f.w;
    }
    __syncthreads();
    const int sb = s_sb, sl = s_sl;

    for (int wb = sb; wb <= sl; wb += WIN) {
        const int we = (wb + WIN - 1 < sl) ? (wb + WIN - 1) : sl;
        const int wlen = we - wb + 1;
        for (int s = tid; s < wlen; s += THREADS) win[s] = 0.0f;
        __syncthreads();

        float acc = vv[0]; int cur = cc[0];
#pragma unroll
        for (int j = 1; j < PER_THREAD; ++j) {
            if (cc[j] == cur) acc += vv[j];
            else {
                if (cur >= wb && cur <= we) atomicAdd(&win[cur - wb], acc);
                cur = cc[j]; acc = vv[j];
            }
        }
        if (cur >= wb && cur <= we) atomicAdd(&win[cur - wb], acc);
        __syncthreads();

        for (int s = tid; s < wlen; s += THREADS) {
            const int g = wb + s;
            const float val = win[s];
            if (g == sb || g == sl) { if (val != 0.0f) atomicAdd(out + g, val); }
            else __builtin_nontemporal_store(val, out + g);
        }
        __syncthreads();
    }
}

// ------------------------------------------------- Fallback (= proven R3)
__global__ __launch_bounds__(THREADS) void fallback_segsum(
    const float* __restrict__ x, const int* __restrict__ ptrs,
    const int* __restrict__ csr, float* __restrict__ out)
{
    __shared__ float seg[LDS_SEGS_FB];
    const int tid = threadIdx.x;
    const long long blk_base = (long long)blockIdx.x * EPB;
    const long long base = blk_base + (long long)tid * PER_THREAD;

    const int seg_base = csr[blk_base];
    const int seg_last = csr[blk_base + EPB - 1];
    const int span = seg_last - seg_base + 1;

    for (int s = tid; s < LDS_SEGS_FB; s += THREADS) seg[s] = 0.0f;

    const vint4* p4 = (const vint4*)(ptrs + base);
    const vint4* c4 = (const vint4*)(csr + base);
    int p[PER_THREAD], c[PER_THREAD];
#pragma unroll
    for (int k = 0; k < PER_THREAD / 4; ++k) {
        vint4 a = __builtin_nontemporal_load(p4 + k);
        vint4 b = __builtin_nontemporal_load(c4 + k);
        p[4 * k + 0] = a.x; p[4 * k + 1] = a.y; p[4 * k + 2] = a.z; p[4 * k + 3] = a.w;
        c[4 * k + 0] = b.x; c[4 * k + 1] = b.y; c[4 * k + 2] = b.z; c[4 * k + 3] = b.w;
    }
    float v[PER_THREAD];
#pragma unroll
    for (int j = 0; j < PER_THREAD; ++j) v[j] = x[p[j]];
    __syncthreads();

    if (span <= LDS_SEGS_FB) {
        float acc = v[0]; int cur = c[0];
#pragma unroll
        for (int j = 1; j < PER_THREAD; ++j) {
            if (c[j] == cur) acc += v[j];
            else { atomicAdd(&seg[cur - seg_base], acc); cur = c[j]; acc = v[j]; }
        }
        atomicAdd(&seg[cur - seg_base], acc);
        __syncthreads();
        for (int s = tid; s < span; s += THREADS) {
            const int g = seg_base + s;
            const float val = seg[s];
            if (s == 0 || g == seg_last) { if (val != 0.0f) atomicAdd(out + g, val); }
            else __builtin_nontemporal_store(val, out + g);
        }
    } else {
        float acc = v[0]; int cur = c[0];
#pragma unroll
        for (int j = 1; j < PER_THREAD; ++j) {
            if (c[j] == cur) acc += v[j];
            else { atomicAdd(out + cur, acc); cur = c[j]; acc = v[j]; }
        }
        atomicAdd(out + cur, acc);
    }
}

extern "C" void kernel_launch(void* const* d_in, const int* in_sizes, int n_in,
                              void* d_out, int out_size, void* d_ws, size_t ws_size,
                              hipStream_t stream) {
    const float* x    = (const float*)d_in[0];
    const int*   ptrs = (const int*)d_in[1];
    const int*   csr  = (const int*)d_in[2];
    float*       out  = (float*)d_out;

    const long long nnz = in_sizes[1];            // 33,554,432
    const int x_size = in_sizes[0];               // 8,388,608

    (void)hipMemsetAsync(d_out, 0, (size_t)out_size * sizeof(float), stream);

    const long long nnzP = nnz / NPASS;           // 16,777,216
    const long long chunksP = nnzP / EPB;         // 4,096
    const bool ok_shapes =
        (nnz % ((long long)NPASS * EPB) == 0) &&
        (x_size % NB == 0) && (x_size / NB == SLICE) &&
        (chunksP == NCH) &&                        // K2 prefix table sizing
        (chunksP % 64 == 0) &&                     // transpose tiling
        nnzP < (long long)INT_MAX / 2;

    const size_t arrBytes  = ((size_t)nnzP * 4 + 255) & ~(size_t)255;       // x3
    const size_t offsBytes = ((size_t)chunksP * NB * 2 + 255) & ~(size_t)255; // x2
    const size_t need      = 3 * arrBytes + 2 * offsBytes + 512;            // ~196 MB

    if (ok_shapes && ws_size >= need) {
        char* w = (char*)d_ws;
        int*            ptrB  = (int*)w;
        int*            csrB  = (int*)(w + arrBytes);
        float*          vbuf  = (float*)(w + 2 * arrBytes);
        unsigned short* offs  = (unsigned short*)(w + 3 * arrBytes);
        unsigned short* offsT = (unsigned short*)(w + 3 * arrBytes + offsBytes);
        const int shift = __builtin_ctz((unsigned)SLICE);   // 15

        for (int g = 0; g < NPASS; ++g) {
            const int* pg = ptrs + (long long)g * nnzP;
            const int* cg = csr  + (long long)g * nnzP;
            k1_bin256   <<<(int)chunksP, THREADS, 0, stream>>>(pg, cg, ptrB, csrB, offs, shift);
            kT_transpose<<<dim3((int)(chunksP / 64), NB / 64), THREADS, 0, stream>>>(offs, offsT, (int)chunksP);
            k2_ldsgather<<<NB, K2T, 0, stream>>>(x, ptrB, offsT, vbuf, (int)chunksP);
            k3_combine  <<<(int)chunksP, THREADS, 0, stream>>>(cg, csrB, vbuf, out);
        }
    } else {
        fallback_segsum<<<(int)(nnz / EPB), THREADS, 0, stream>>>(x, ptrs, csr, out);
    }
}

// Round 11
// 505.939 us; speedup vs baseline: 1.3398x; 1.0138x over previous
//
#include <hip/hip_runtime.h>
#include <hip/hip_bf16.h>
#include <climits>

// out[csr[i]] += x[ptrs[i]]
//   X_SIZE = 8,388,608 f32 (32 MB), NNZ = 33,554,432, N_SEG = 8,388,608, csr SORTED.
//
// R10 post-mortem: K2 = 13 LDS ops/entry (12-step dependent binary search) at
// 16 waves/CU -> 104us; K3 latency-bound at 16 waves/CU (WIN=8192 -> 33KB LDS
// -> 4 blocks/CU) -> 103us.
// R11: K2 bin->run lookup table (64-flat bins; 1 table read + ~2 advance + 1
// gather = 4 LDS ops, chain 12->3). K3 WIN=2048 -> 8 blocks/CU (32 waves).
// K1/kT unchanged (K1 is at its BW roofline).

#define THREADS 256
#define PER_THREAD 16
#define EPB (THREADS * PER_THREAD)   // 4096 entries per chunk
#define NB 256                       // buckets; slice = 128 KiB
#define SLICE 32768                  // floats per slice (= X_SIZE / NB)
#define NPASS 2
#define K2T 1024                     // K2 block size
#define K2U 8                        // flat entries per thread per tile
#define NCH 4096                     // chunks per pass (guarded)
#define NBIN 1152                    // K2 bin table (64 flats/bin; >= 1024 scan scratch)
#define WIN 2048                     // K3 LDS window (8 KB -> 8 blocks/CU)
#define LDS_SEGS_FB 4096

typedef int   vint4   __attribute__((ext_vector_type(4)));
typedef float vfloat4 __attribute__((ext_vector_type(4)));

// ---------------------------------------------------------------- K1
// Chunk-local 256-way bin (unchanged, proven, BW-bound).
__global__ __launch_bounds__(THREADS) void k1_bin256(
    const int* __restrict__ ptrs, const int* __restrict__ csr,
    int* __restrict__ ptrB, int* __restrict__ csrB,
    unsigned short* __restrict__ offs, int shift)
{
    __shared__ int  hist[NB];
    __shared__ int  scanb[NB];
    __shared__ int  curs[NB];
    __shared__ int2 buf[EPB];                 // 32 KB

    const int tid = threadIdx.x;              // THREADS == NB == 256
    const long long cb = (long long)blockIdx.x * EPB;
    const long long base = cb + (long long)tid * PER_THREAD;

    const vint4* p4 = (const vint4*)(ptrs + base);
    const vint4* c4 = (const vint4*)(csr + base);
    int p[PER_THREAD], c[PER_THREAD];
#pragma unroll
    for (int k = 0; k < PER_THREAD / 4; ++k) {
        vint4 a = __builtin_nontemporal_load(p4 + k);
        vint4 b = __builtin_nontemporal_load(c4 + k);
        p[4 * k + 0] = a.x; p[4 * k + 1] = a.y; p[4 * k + 2] = a.z; p[4 * k + 3] = a.w;
        c[4 * k + 0] = b.x; c[4 * k + 1] = b.y; c[4 * k + 2] = b.z; c[4 * k + 3] = b.w;
    }

    hist[tid] = 0;
    __syncthreads();
#pragma unroll
    for (int j = 0; j < PER_THREAD; ++j)
        atomicAdd(&hist[p[j] >> shift], 1);
    __syncthreads();

    const int hv = hist[tid];
    scanb[tid] = hv;
    __syncthreads();
    for (int d = 1; d < NB; d <<= 1) {
        int u = (tid >= d) ? scanb[tid - d] : 0;
        __syncthreads();
        scanb[tid] += u;
        __syncthreads();
    }
    const int excl = scanb[tid] - hv;         // exclusive prefix
    curs[tid] = excl;
    offs[(size_t)blockIdx.x * NB + tid] = (unsigned short)excl;
    __syncthreads();

#pragma unroll
    for (int j = 0; j < PER_THREAD; ++j) {
        const int b = p[j] >> shift;
        const int pos = atomicAdd(&curs[b], 1);
        buf[pos] = make_int2(p[j], c[j]);
    }
    __syncthreads();

    for (int i = tid; i < EPB; i += THREADS) {
        int2 e = buf[i];
        __builtin_nontemporal_store(e.x, ptrB + cb + i);
        __builtin_nontemporal_store(e.y, csrB + cb + i);
    }
}

// ---------------------------------------------------------------- kT
// offs [chunksP][NB] ushort -> offsT [NB][chunksP] (unchanged, proven).
__global__ __launch_bounds__(THREADS) void kT_transpose(
    const unsigned short* __restrict__ in, unsigned short* __restrict__ out,
    int chunksP)
{
    __shared__ unsigned short t[64][65];
    const int c  = threadIdx.x & 63;
    const int r4 = threadIdx.x >> 6;
    const int j0 = blockIdx.x * 64;
    const int b0 = blockIdx.y * 64;
    for (int rr = r4; rr < 64; rr += 4)
        t[rr][c] = in[(size_t)(j0 + rr) * NB + b0 + c];
    __syncthreads();
    for (int rr = r4; rr < 64; rr += 4)
        out[(size_t)(b0 + rr) * chunksP + j0 + c] = t[c][rr];
}

// ---------------------------------------------------------------- K2
// Block b: stage x slice (128 KiB) + pfx + run-starts + bin->run table in LDS.
// Lane-major flat iteration (wave = 64 consecutive flats, ~5 lines on ptrB/v).
// Lookup: j = table[f>>6] then advance while pfx[j+1] <= f (~1-2 steps).
// ~4 LDS ops/entry vs 13 with binary search; chain depth 3 vs 12.
__global__ __launch_bounds__(K2T) void k2_ldsgather(
    const float* __restrict__ x, const int* __restrict__ ptrB,
    const unsigned short* __restrict__ offsT, float* __restrict__ v,
    int chunksP)
{
    __shared__ float          sl[SLICE];      // 128 KiB
    __shared__ int            pfx[NCH];       // 16 KiB (excl prefix of run lens)
    __shared__ unsigned short srs[NCH];       // 8 KiB (run starts within chunk)
    __shared__ int            table[NBIN];    // 4.5 KiB (scan scratch, then bin->run)
    __shared__ int            sTot;

    const int tid = threadIdx.x;
    const int b = blockIdx.x;
    const bool lastB = (b == NB - 1);

    // stage slice (read exactly once per pass)
    const vfloat4* xs = (const vfloat4*)(x + (size_t)b * SLICE);
    vfloat4* ls = (vfloat4*)sl;
    for (int i = tid; i < SLICE / 4; i += K2T)
        ls[i] = __builtin_nontemporal_load(xs + i);

    // run starts + lengths for this bucket across all chunks
    const unsigned short* rowS = offsT + (size_t)b * chunksP;
    const unsigned short* rowE = offsT + (size_t)(b + 1) * chunksP;
    for (int j = tid; j < NCH; j += K2T) {
        const int s = rowS[j];
        const int e = lastB ? EPB : (int)rowE[j];
        srs[j] = (unsigned short)s;
        pfx[j] = e - s;
    }
    __syncthreads();

    // block scan of run lengths (table[] as scratch): 4/thread -> 1024-wide
    const int bse = tid * 4;
    const int l0 = pfx[bse], l1 = pfx[bse + 1], l2 = pfx[bse + 2], l3 = pfx[bse + 3];
    const int lsum = l0 + l1 + l2 + l3;
    table[tid] = lsum;
    __syncthreads();
    for (int d = 1; d < K2T; d <<= 1) {
        int u = (tid >= d) ? table[tid - d] : 0;
        __syncthreads();
        table[tid] += u;
        __syncthreads();
    }
    const int texcl = table[tid] - lsum;
    if (tid == K2T - 1) sTot = texcl + lsum;
    __syncthreads();                          // all table reads done; sTot visible
    pfx[bse]     = texcl;
    pfx[bse + 1] = texcl + l0;
    pfx[bse + 2] = texcl + l0 + l1;
    pfx[bse + 3] = texcl + l0 + l1 + l2;
    __syncthreads();
    const int T = sTot;

    // build bin->run table: run j owns bins [ceil(pfx[j]/64), ceil(pfxNext/64))
    // (write-disjoint, covers [0, ceil(T/64)) exactly; no atomics needed)
#pragma unroll
    for (int q = 0; q < 4; ++q) {
        const int j  = bse + q;
        const int pj = pfx[j];
        const int pn = (j == NCH - 1) ? T : pfx[j + 1];
        int b0 = (pj + 63) >> 6;
        int b1 = (pn + 63) >> 6;
        if (b0 > NBIN) b0 = NBIN;
        if (b1 > NBIN) b1 = NBIN;
        for (int bb = b0; bb < b1; ++bb) table[bb] = j;
    }
    __syncthreads();

    for (int fb = 0; fb < T; fb += K2T * K2U) {
        // 8 independent run lookups (lane-major: wave = 64 consecutive flats)
        int gi[K2U];
#pragma unroll
        for (int k = 0; k < K2U; ++k) {
            const int f = fb + k * K2T + tid;
            if (f < T) {
                int bb = f >> 6;
                if (bb >= NBIN) bb = NBIN - 1;        // freak-T guard (correct, slow)
                int j = table[bb];                    // pfx[j] <= f guaranteed
                while (j + 1 < NCH && pfx[j + 1] <= f) ++j;
                gi[k] = j * EPB + (int)srs[j] + (f - pfx[j]);
            } else gi[k] = -1;
        }
        // batch ptr loads (~5 lines per wave-instr)
        int pi[K2U];
#pragma unroll
        for (int k = 0; k < K2U; ++k)
            pi[k] = (gi[k] >= 0) ? ptrB[gi[k]] : 0;
        // LDS gathers
        float va[K2U];
#pragma unroll
        for (int k = 0; k < K2U; ++k)
            va[k] = sl[pi[k] & (SLICE - 1)];
        // batch stores (~5 lines per wave-instr)
#pragma unroll
        for (int k = 0; k < K2U; ++k)
            if (gi[k] >= 0) v[gi[k]] = va[k];
    }
}

// ---------------------------------------------------------------- K3
// Block per chunk: dense LDS window (WIN=2048 -> 8 blocks/CU, 32 waves);
// interior segs exclusively owned (csr sorted) -> nt store; first/last seg
// atomic. Order-agnostic (csrB scrambled within chunk).
__global__ __launch_bounds__(THREADS) void k3_combine(
    const int* __restrict__ csrOrig, const int* __restrict__ csrB,
    const float* __restrict__ v, float* __restrict__ out)
{
    __shared__ float win[WIN];
    __shared__ int s_sb, s_sl;

    const int tid = threadIdx.x;
    const long long cb = (long long)blockIdx.x * EPB;

    if (tid == 0) { s_sb = csrOrig[cb]; s_sl = csrOrig[cb + EPB - 1]; }

    const vint4*   c4 = (const vint4*)(csrB + cb + (long long)tid * PER_THREAD);
    const vfloat4* v4 = (const vfloat4*)(v + cb + (long long)tid * PER_THREAD);
    int cc[PER_THREAD]; float vv[PER_THREAD];
#pragma unroll
    for (int k = 0; k < PER_THREAD / 4; ++k) {
        vint4   a = __builtin_nontemporal_load(c4 + k);
        vfloat4 f = __builtin_nontemporal_load(v4 + k);
        cc[4 * k + 0] = a.x; cc[4 * k + 1] = a.y; cc[4 * k + 2] = a.z; cc[4 * k + 3] = a.w;
        vv[4 * k + 0] = f.x; vv[4 * k + 1] = f.y; vv[4 * k + 2] = f.z; vv[4 * k + 3] = f.w;
    }
    __syncthreads();
    const int sb = s_sb, sl = s_sl;

    for (int wb = sb; wb <= sl; wb += WIN) {
        const int we = (wb + WIN - 1 < sl) ? (wb + WIN - 1) : sl;
        const int wlen = we - wb + 1;
        for (int s = tid; s < wlen; s += THREADS) win[s] = 0.0f;
        __syncthreads();

        float acc = vv[0]; int cur = cc[0];
#pragma unroll
        for (int j = 1; j < PER_THREAD; ++j) {
            if (cc[j] == cur) acc += vv[j];
            else {
                if (cur >= wb && cur <= we) atomicAdd(&win[cur - wb], acc);
                cur = cc[j]; acc = vv[j];
            }
        }
        if (cur >= wb && cur <= we) atomicAdd(&win[cur - wb], acc);
        __syncthreads();

        for (int s = tid; s < wlen; s += THREADS) {
            const int g = wb + s;
            const float val = win[s];
            if (g == sb || g == sl) { if (val != 0.0f) atomicAdd(out + g, val); }
            else __builtin_nontemporal_store(val, out + g);
        }
        __syncthreads();
    }
}

// ------------------------------------------------- Fallback (= proven R3)
__global__ __launch_bounds__(THREADS) void fallback_segsum(
    const float* __restrict__ x, const int* __restrict__ ptrs,
    const int* __restrict__ csr, float* __restrict__ out)
{
    __shared__ float seg[LDS_SEGS_FB];
    const int tid = threadIdx.x;
    const long long blk_base = (long long)blockIdx.x * EPB;
    const long long base = blk_base + (long long)tid * PER_THREAD;

    const int seg_base = csr[blk_base];
    const int seg_last = csr[blk_base + EPB - 1];
    const int span = seg_last - seg_base + 1;

    for (int s = tid; s < LDS_SEGS_FB; s += THREADS) seg[s] = 0.0f;

    const vint4* p4 = (const vint4*)(ptrs + base);
    const vint4* c4 = (const vint4*)(csr + base);
    int p[PER_THREAD], c[PER_THREAD];
#pragma unroll
    for (int k = 0; k < PER_THREAD / 4; ++k) {
        vint4 a = __builtin_nontemporal_load(p4 + k);
        vint4 b = __builtin_nontemporal_load(c4 + k);
        p[4 * k + 0] = a.x; p[4 * k + 1] = a.y; p[4 * k + 2] = a.z; p[4 * k + 3] = a.w;
        c[4 * k + 0] = b.x; c[4 * k + 1] = b.y; c[4 * k + 2] = b.z; c[4 * k + 3] = b.w;
    }
    float v[PER_THREAD];
#pragma unroll
    for (int j = 0; j < PER_THREAD; ++j) v[j] = x[p[j]];
    __syncthreads();

    if (span <= LDS_SEGS_FB) {
        float acc = v[0]; int cur = c[0];
#pragma unroll
        for (int j = 1; j < PER_THREAD; ++j) {
            if (c[j] == cur) acc += v[j];
            else { atomicAdd(&seg[cur - seg_base], acc); cur = c[j]; acc = v[j]; }
        }
        atomicAdd(&seg[cur - seg_base], acc);
        __syncthreads();
        for (int s = tid; s < span; s += THREADS) {
            const int g = seg_base + s;
            const float val = seg[s];
            if (s == 0 || g == seg_last) { if (val != 0.0f) atomicAdd(out + g, val); }
            else __builtin_nontemporal_store(val, out + g);
        }
    } else {
        float acc = v[0]; int cur = c[0];
#pragma unroll
        for (int j = 1; j < PER_THREAD; ++j) {
            if (c[j] == cur) acc += v[j];
            else { atomicAdd(out + cur, acc); cur = c[j]; acc = v[j]; }
        }
        atomicAdd(out + cur, acc);
    }
}

extern "C" void kernel_launch(void* const* d_in, const int* in_sizes, int n_in,
                              void* d_out, int out_size, void* d_ws, size_t ws_size,
                              hipStream_t stream) {
    const float* x    = (const float*)d_in[0];
    const int*   ptrs = (const int*)d_in[1];
    const int*   csr  = (const int*)d_in[2];
    float*       out  = (float*)d_out;

    const long long nnz = in_sizes[1];            // 33,554,432
    const int x_size = in_sizes[0];               // 8,388,608

    (void)hipMemsetAsync(d_out, 0, (size_t)out_size * sizeof(float), stream);

    const long long nnzP = nnz / NPASS;           // 16,777,216
    const long long chunksP = nnzP / EPB;         // 4,096
    const bool ok_shapes =
        (nnz % ((long long)NPASS * EPB) == 0) &&
        (x_size % NB == 0) && (x_size / NB == SLICE) &&
        (chunksP == NCH) &&                        // K2 prefix table sizing
        (chunksP % 64 == 0) &&                     // transpose tiling
        nnzP < (long long)INT_MAX / 2;

    const size_t arrBytes  = ((size_t)nnzP * 4 + 255) & ~(size_t)255;       // x3
    const size_t offsBytes = ((size_t)chunksP * NB * 2 + 255) & ~(size_t)255; // x2
    const size_t need      = 3 * arrBytes + 2 * offsBytes + 512;            // ~196 MB

    if (ok_shapes && ws_size >= need) {
        char* w = (char*)d_ws;
        int*            ptrB  = (int*)w;
        int*            csrB  = (int*)(w + arrBytes);
        float*          vbuf  = (float*)(w + 2 * arrBytes);
        unsigned short* offs  = (unsigned short*)(w + 3 * arrBytes);
        unsigned short* offsT = (unsigned short*)(w + 3 * arrBytes + offsBytes);
        const int shift = __builtin_ctz((unsigned)SLICE);   // 15

        for (int g = 0; g < NPASS; ++g) {
            const int* pg = ptrs + (long long)g * nnzP;
            const int* cg = csr  + (long long)g * nnzP;
            k1_bin256   <<<(int)chunksP, THREADS, 0, stream>>>(pg, cg, ptrB, csrB, offs, shift);
            kT_transpose<<<dim3((int)(chunksP / 64), NB / 64), THREADS, 0, stream>>>(offs, offsT, (int)chunksP);
            k2_ldsgather<<<NB, K2T, 0, stream>>>(x, ptrB, offsT, vbuf, (int)chunksP);
            k3_combine  <<<(int)chunksP, THREADS, 0, stream>>>(cg, csrB, vbuf, out);
        }
    } else {
        fallback_segsum<<<(int)(nnz / EPB), THREADS, 0, stream>>>(x, ptrs, csr, out);
    }
}

// Round 12
// 469.093 us; speedup vs baseline: 1.4450x; 1.0785x over previous
//
#include <hip/hip_runtime.h>
#include <hip/hip_bf16.h>
#include <climits>

// out[csr[i]] += x[ptrs[i]]
//   X_SIZE = 8,388,608 f32 (32 MB), NNZ = 33,554,432, N_SEG = 8,388,608, csr SORTED.
//
// R11 post-mortem: K2 stuck at 103us across 3 lookup structures -> limiter is
// the DEPENDENT, BRANCHING advance (ds_read->waitcnt->branch per step, per k),
// not LDS op count. R12: branchless parallel-probe lookup: packed (pfx<<13|srs)
// single array + 32-flat bin table; j0=table[f>>5]; 5 INDEPENDENT probe reads;
// advance = sum of compares; cndmask select; sentinel-guarded rare tail.
// Chain depth 2 LDS latencies; 8 k-lookups fully ILP'd. K1/kT/K3 unchanged.

#define THREADS 256
#define PER_THREAD 16
#define EPB (THREADS * PER_THREAD)   // 4096 entries per chunk
#define NB 256                       // buckets; slice = 128 KiB
#define SLICE 32768                  // floats per slice (= X_SIZE / NB)
#define NPASS 2
#define K2T 1024                     // K2 block size
#define K2U 8                        // flat entries per thread per tile
#define NCH 4096                     // chunks per pass (guarded)
#define NBIN 2304                    // bin->run table, 32 flats/bin (covers T<=73728)
#define WIN 2048                     // K3 LDS window (8 KB)
#define LDS_SEGS_FB 4096

typedef int   vint4   __attribute__((ext_vector_type(4)));
typedef float vfloat4 __attribute__((ext_vector_type(4)));

// ---------------------------------------------------------------- K1
// Chunk-local 256-way bin (unchanged, proven, BW-bound).
__global__ __launch_bounds__(THREADS) void k1_bin256(
    const int* __restrict__ ptrs, const int* __restrict__ csr,
    int* __restrict__ ptrB, int* __restrict__ csrB,
    unsigned short* __restrict__ offs, int shift)
{
    __shared__ int  hist[NB];
    __shared__ int  scanb[NB];
    __shared__ int  curs[NB];
    __shared__ int2 buf[EPB];                 // 32 KB

    const int tid = threadIdx.x;              // THREADS == NB == 256
    const long long cb = (long long)blockIdx.x * EPB;
    const long long base = cb + (long long)tid * PER_THREAD;

    const vint4* p4 = (const vint4*)(ptrs + base);
    const vint4* c4 = (const vint4*)(csr + base);
    int p[PER_THREAD], c[PER_THREAD];
#pragma unroll
    for (int k = 0; k < PER_THREAD / 4; ++k) {
        vint4 a = __builtin_nontemporal_load(p4 + k);
        vint4 b = __builtin_nontemporal_load(c4 + k);
        p[4 * k + 0] = a.x; p[4 * k + 1] = a.y; p[4 * k + 2] = a.z; p[4 * k + 3] = a.w;
        c[4 * k + 0] = b.x; c[4 * k + 1] = b.y; c[4 * k + 2] = b.z; c[4 * k + 3] = b.w;
    }

    hist[tid] = 0;
    __syncthreads();
#pragma unroll
    for (int j = 0; j < PER_THREAD; ++j)
        atomicAdd(&hist[p[j] >> shift], 1);
    __syncthreads();

    const int hv = hist[tid];
    scanb[tid] = hv;
    __syncthreads();
    for (int d = 1; d < NB; d <<= 1) {
        int u = (tid >= d) ? scanb[tid - d] : 0;
        __syncthreads();
        scanb[tid] += u;
        __syncthreads();
    }
    const int excl = scanb[tid] - hv;         // exclusive prefix
    curs[tid] = excl;
    offs[(size_t)blockIdx.x * NB + tid] = (unsigned short)excl;
    __syncthreads();

#pragma unroll
    for (int j = 0; j < PER_THREAD; ++j) {
        const int b = p[j] >> shift;
        const int pos = atomicAdd(&curs[b], 1);
        buf[pos] = make_int2(p[j], c[j]);
    }
    __syncthreads();

    for (int i = tid; i < EPB; i += THREADS) {
        int2 e = buf[i];
        __builtin_nontemporal_store(e.x, ptrB + cb + i);
        __builtin_nontemporal_store(e.y, csrB + cb + i);
    }
}

// ---------------------------------------------------------------- kT
// offs [chunksP][NB] ushort -> offsT [NB][chunksP] (unchanged, proven).
__global__ __launch_bounds__(THREADS) void kT_transpose(
    const unsigned short* __restrict__ in, unsigned short* __restrict__ out,
    int chunksP)
{
    __shared__ unsigned short t[64][65];
    const int c  = threadIdx.x & 63;
    const int r4 = threadIdx.x >> 6;
    const int j0 = blockIdx.x * 64;
    const int b0 = blockIdx.y * 64;
    for (int rr = r4; rr < 64; rr += 4)
        t[rr][c] = in[(size_t)(j0 + rr) * NB + b0 + c];
    __syncthreads();
    for (int rr = r4; rr < 64; rr += 4)
        out[(size_t)(b0 + rr) * chunksP + j0 + c] = t[c][rr];
}

// ---------------------------------------------------------------- K2
// Block b: x slice (128 KiB) + packed run table (pfx<<13|srs) + 32-flat-bin
// lookup table in LDS. Lane-major flat iteration. Lookup = 1 table read + 5
// PARALLEL probe reads + branchless select; sentinel-guarded rare tail loop.
__global__ __launch_bounds__(K2T) void k2_ldsgather(
    const float* __restrict__ x, const int* __restrict__ ptrB,
    const unsigned short* __restrict__ offsT, float* __restrict__ v,
    int chunksP)
{
    __shared__ float sl[SLICE];               // 128 KiB
    __shared__ int   packed[NCH + 8];         // 16 KiB (pfx<<13 | srs) + sentinels
    __shared__ int   table[NBIN];             // 9 KiB (scan scratch, then bin->run)
    __shared__ int   sTot;

    const int tid = threadIdx.x;
    const int b = blockIdx.x;
    const bool lastB = (b == NB - 1);

    // stage slice (read exactly once per pass)
    const vfloat4* xs = (const vfloat4*)(x + (size_t)b * SLICE);
    vfloat4* ls = (vfloat4*)sl;
    for (int i = tid; i < SLICE / 4; i += K2T)
        ls[i] = __builtin_nontemporal_load(xs + i);

    // this thread's 4 runs: starts + lengths (kept in registers)
    const unsigned short* rowS = offsT + (size_t)b * chunksP;
    const unsigned short* rowE = offsT + (size_t)(b + 1) * chunksP;
    const int q0 = tid * 4;
    const int s0 = rowS[q0], s1 = rowS[q0 + 1], s2 = rowS[q0 + 2], s3 = rowS[q0 + 3];
    const int e0 = lastB ? EPB : (int)rowE[q0];
    const int e1 = lastB ? EPB : (int)rowE[q0 + 1];
    const int e2 = lastB ? EPB : (int)rowE[q0 + 2];
    const int e3 = lastB ? EPB : (int)rowE[q0 + 3];
    const int l0 = e0 - s0, l1 = e1 - s1, l2 = e2 - s2, l3 = e3 - s3;
    const int lsum = l0 + l1 + l2 + l3;

    // 1024-wide Hillis-Steele scan of per-thread sums (table as scratch)
    table[tid] = lsum;
    __syncthreads();
    for (int d = 1; d < K2T; d <<= 1) {
        int u = (tid >= d) ? table[tid - d] : 0;
        __syncthreads();
        table[tid] += u;
        __syncthreads();
    }
    const int texcl = table[tid] - lsum;
    if (tid == K2T - 1) sTot = texcl + lsum;
    __syncthreads();                          // table reads done; sTot visible
    const int T = sTot;

    // in-register prefixes for my 4 runs (+ end = texcl+lsum)
    const int p0 = texcl, p1 = texcl + l0, p2 = p1 + l1, p3 = p2 + l2, p4 = texcl + lsum;

    // packed run table + sentinels
    packed[q0]     = (p0 << 13) | s0;
    packed[q0 + 1] = (p1 << 13) | s1;
    packed[q0 + 2] = (p2 << 13) | s2;
    packed[q0 + 3] = (p3 << 13) | s3;
    if (tid < 8) packed[NCH + tid] = (T << 13);   // pfx = T: probe never advances past

    // bin->run table: run j owns bins [ceil(pfx/32), ceil(pfxNext/32))
    {
        const int pa[5] = { p0, p1, p2, p3, p4 };
#pragma unroll
        for (int q = 0; q < 4; ++q) {
            int b0_ = (pa[q] + 31) >> 5;
            int b1_ = (pa[q + 1] + 31) >> 5;
            if (b0_ > NBIN) b0_ = NBIN;
            if (b1_ > NBIN) b1_ = NBIN;
            for (int bb = b0_; bb < b1_; ++bb) table[bb] = q0 + q;
        }
    }
    __syncthreads();

    for (int fb = 0; fb < T; fb += K2T * K2U) {
        int gi[K2U];
#pragma unroll
        for (int k = 0; k < K2U; ++k) {
            const int f = fb + k * K2T + tid;
            const bool valid = (f < T);
            const int fe = valid ? f : 0;     // safe reads, result discarded
            int bb = fe >> 5;
            if (bb >= NBIN) bb = NBIN - 1;    // freak-T guard (correct, slow path)
            const int j0j = table[bb];        // run with pfx <= bin start
            // 5 INDEPENDENT probes (sentinels make j0j+5 always in-bounds)
            const int pk0 = packed[j0j];
            const int pk1 = packed[j0j + 1];
            const int pk2 = packed[j0j + 2];
            const int pk3 = packed[j0j + 3];
            const int pk4 = packed[j0j + 4];
            const int pk5 = packed[j0j + 5];
            const int i1 = ((pk1 >> 13) <= fe);
            const int i2 = ((pk2 >> 13) <= fe);
            const int i3 = ((pk3 >> 13) <= fe);
            const int i4 = ((pk4 >> 13) <= fe);
            const int i5 = ((pk5 >> 13) <= fe);
            int jp = j0j + i1 + i2 + i3 + i4 + i5;
            int sel = pk0;
            sel = i1 ? pk1 : sel;
            sel = i2 ? pk2 : sel;
            sel = i3 ? pk3 : sel;
            sel = i4 ? pk4 : sel;
            sel = i5 ? pk5 : sel;
            if (i5) {                         // rare tail (~0.4%/lane)
                while ((packed[jp + 1] >> 13) <= fe) ++jp;
                sel = packed[jp];
            }
            const int g = jp * EPB + (sel & 0x1FFF) + (fe - (sel >> 13));
            gi[k] = valid ? g : -1;
        }
        // batch ptr loads (~5 lines per wave-instr)
        int pi[K2U];
#pragma unroll
        for (int k = 0; k < K2U; ++k)
            pi[k] = (gi[k] >= 0) ? ptrB[gi[k]] : 0;
        // LDS gathers
        float va[K2U];
#pragma unroll
        for (int k = 0; k < K2U; ++k)
            va[k] = sl[pi[k] & (SLICE - 1)];
        // batch stores (~5 lines per wave-instr)
#pragma unroll
        for (int k = 0; k < K2U; ++k)
            if (gi[k] >= 0) v[gi[k]] = va[k];
    }
}

// ---------------------------------------------------------------- K3
// Block per chunk: dense LDS window; interior segs exclusively owned (csr
// sorted) -> nt store; first/last seg atomic. Order-agnostic (unchanged).
__global__ __launch_bounds__(THREADS) void k3_combine(
    const int* __restrict__ csrOrig, const int* __restrict__ csrB,
    const float* __restrict__ v, float* __restrict__ out)
{
    __shared__ float win[WIN];
    __shared__ int s_sb, s_sl;

    const int tid = threadIdx.x;
    const long long cb = (long long)blockIdx.x * EPB;

    if (tid == 0) { s_sb = csrOrig[cb]; s_sl = csrOrig[cb + EPB - 1]; }

    const vint4*   c4 = (const vint4*)(csrB + cb + (long long)tid * PER_THREAD);
    const vfloat4* v4 = (const vfloat4*)(v + cb + (long long)tid * PER_THREAD);
    int cc[PER_THREAD]; float vv[PER_THREAD];
#pragma unroll
    for (int k = 0; k < PER_THREAD / 4; ++k) {
        vint4   a = __builtin_nontemporal_load(c4 + k);
        vfloat4 f = __builtin_nontemporal_load(v4 + k);
        cc[4 * k + 0] = a.x; cc[4 * k + 1] = a.y; cc[4 * k + 2] = a.z; cc[4 * k + 3] = a.w;
        vv[4 * k + 0] = f.x; vv[4 * k + 1] = f.y; vv[4 * k + 2] = f.z; vv[4 * k + 3] = f.w;
    }
    __syncthreads();
    const int sb = s_sb, sl = s_sl;

    for (int wb = sb; wb <= sl; wb += WIN) {
        const int we = (wb + WIN - 1 < sl) ? (wb + WIN - 1) : sl;
        const int wlen = we - wb + 1;
        for (int s = tid; s < wlen; s += THREADS) win[s] = 0.0f;
        __syncthreads();

        float acc = vv[0]; int cur = cc[0];
#pragma unroll
        for (int j = 1; j < PER_THREAD; ++j) {
            if (cc[j] == cur) acc += vv[j];
            else {
                if (cur >= wb && cur <= we) atomicAdd(&win[cur - wb], acc);
                cur = cc[j]; acc = vv[j];
            }
        }
        if (cur >= wb && cur <= we) atomicAdd(&win[cur - wb], acc);
        __syncthreads();

        for (int s = tid; s < wlen; s += THREADS) {
            const int g = wb + s;
            const float val = win[s];
            if (g == sb || g == sl) { if (val != 0.0f) atomicAdd(out + g, val); }
            else __builtin_nontemporal_store(val, out + g);
        }
        __syncthreads();
    }
}

// ------------------------------------------------- Fallback (= proven R3)
__global__ __launch_bounds__(THREADS) void fallback_segsum(
    const float* __restrict__ x, const int* __restrict__ ptrs,
    const int* __restrict__ csr, float* __restrict__ out)
{
    __shared__ float seg[LDS_SEGS_FB];
    const int tid = threadIdx.x;
    const long long blk_base = (long long)blockIdx.x * EPB;
    const long long base = blk_base + (long long)tid * PER_THREAD;

    const int seg_base = csr[blk_base];
    const int seg_last = csr[blk_base + EPB - 1];
    const int span = seg_last - seg_base + 1;

    for (int s = tid; s < LDS_SEGS_FB; s += THREADS) seg[s] = 0.0f;

    const vint4* p4 = (const vint4*)(ptrs + base);
    const vint4* c4 = (const vint4*)(csr + base);
    int p[PER_THREAD], c[PER_THREAD];
#pragma unroll
    for (int k = 0; k < PER_THREAD / 4; ++k) {
        vint4 a = __builtin_nontemporal_load(p4 + k);
        vint4 b = __builtin_nontemporal_load(c4 + k);
        p[4 * k + 0] = a.x; p[4 * k + 1] = a.y; p[4 * k + 2] = a.z; p[4 * k + 3] = a.w;
        c[4 * k + 0] = b.x; c[4 * k + 1] = b.y; c[4 * k + 2] = b.z; c[4 * k + 3] = b.w;
    }
    float v[PER_THREAD];
#pragma unroll
    for (int j = 0; j < PER_THREAD; ++j) v[j] = x[p[j]];
    __syncthreads();

    if (span <= LDS_SEGS_FB) {
        float acc = v[0]; int cur = c[0];
#pragma unroll
        for (int j = 1; j < PER_THREAD; ++j) {
            if (c[j] == cur) acc += v[j];
            else { atomicAdd(&seg[cur - seg_base], acc); cur = c[j]; acc = v[j]; }
        }
        atomicAdd(&seg[cur - seg_base], acc);
        __syncthreads();
        for (int s = tid; s < span; s += THREADS) {
            const int g = seg_base + s;
            const float val = seg[s];
            if (s == 0 || g == seg_last) { if (val != 0.0f) atomicAdd(out + g, val); }
            else __builtin_nontemporal_store(val, out + g);
        }
    } else {
        float acc = v[0]; int cur = c[0];
#pragma unroll
        for (int j = 1; j < PER_THREAD; ++j) {
            if (c[j] == cur) acc += v[j];
            else { atomicAdd(out + cur, acc); cur = c[j]; acc = v[j]; }
        }
        atomicAdd(out + cur, acc);
    }
}

extern "C" void kernel_launch(void* const* d_in, const int* in_sizes, int n_in,
                              void* d_out, int out_size, void* d_ws, size_t ws_size,
                              hipStream_t stream) {
    const float* x    = (const float*)d_in[0];
    const int*   ptrs = (const int*)d_in[1];
    const int*   csr  = (const int*)d_in[2];
    float*       out  = (float*)d_out;

    const long long nnz = in_sizes[1];            // 33,554,432
    const int x_size = in_sizes[0];               // 8,388,608

    (void)hipMemsetAsync(d_out, 0, (size_t)out_size * sizeof(float), stream);

    const long long nnzP = nnz / NPASS;           // 16,777,216
    const long long chunksP = nnzP / EPB;         // 4,096
    const bool ok_shapes =
        (nnz % ((long long)NPASS * EPB) == 0) &&
        (x_size % NB == 0) && (x_size / NB == SLICE) &&
        (chunksP == NCH) &&                        // K2 table sizing + scan width
        (chunksP % 64 == 0) &&                     // transpose tiling
        nnzP < (long long)INT_MAX / 2;

    const size_t arrBytes  = ((size_t)nnzP * 4 + 255) & ~(size_t)255;       // x3
    const size_t offsBytes = ((size_t)chunksP * NB * 2 + 255) & ~(size_t)255; // x2
    const size_t need      = 3 * arrBytes + 2 * offsBytes + 512;            // ~196 MB

    if (ok_shapes && ws_size >= need) {
        char* w = (char*)d_ws;
        int*            ptrB  = (int*)w;
        int*            csrB  = (int*)(w + arrBytes);
        float*          vbuf  = (float*)(w + 2 * arrBytes);
        unsigned short* offs  = (unsigned short*)(w + 3 * arrBytes);
        unsigned short* offsT = (unsigned short*)(w + 3 * arrBytes + offsBytes);
        const int shift = __builtin_ctz((unsigned)SLICE);   // 15

        for (int g = 0; g < NPASS; ++g) {
            const int* pg = ptrs + (long long)g * nnzP;
            const int* cg = csr  + (long long)g * nnzP;
            k1_bin256   <<<(int)chunksP, THREADS, 0, stream>>>(pg, cg, ptrB, csrB, offs, shift);
            kT_transpose<<<dim3((int)(chunksP / 64), NB / 64), THREADS, 0, stream>>>(offs, offsT, (int)chunksP);
            k2_ldsgather<<<NB, K2T, 0, stream>>>(x, ptrB, offsT, vbuf, (int)chunksP);
            k3_combine  <<<(int)chunksP, THREADS, 0, stream>>>(cg, csrB, vbuf, out);
        }
    } else {
        fallback_segsum<<<(int)(nnz / EPB), THREADS, 0, stream>>>(x, ptrs, csr, out);
    }
}

// Round 13
// 431.557 us; speedup vs baseline: 1.5707x; 1.0870x over previous
//
#include <hip/hip_runtime.h>
#include <hip/hip_bf16.h>
#include <climits>

// out[csr[i]] += x[ptrs[i]]
//   X_SIZE = 8,388,608 f32 (32 MB), NNZ = 33,554,432, N_SEG = 8,388,608, csr SORTED.
//
// R12 post-mortem: K2 fixed (branchless probe). K3 now the wall: 97us/pass,
// all counters low = latency-bound (1 chunk/block, 3 barrier-separated short
// phases, nothing to overlap). R13:
//  - ushort packing: ptrB = p&32767 (15b), csrB = csr - chunkFirst (rel, span
//    ~1024±36; 64KB overflow is ~1800 sigma). K1 writes chunkInfo=(first,span).
//  - K3: 2 chunks per block (grid 2048), ALL loads for both chunks issued up
//    front -> chunk B's HBM latency hides under chunk A's zero/atomic/flush.
//  - K1 writeout pair-packs ushorts into 4B nt stores. K2 reads ushort ptrB.

#define THREADS 256
#define PER_THREAD 16
#define EPB (THREADS * PER_THREAD)   // 4096 entries per chunk
#define NB 256                       // buckets; slice = 128 KiB
#define SLICE 32768                  // floats per slice (= X_SIZE / NB)
#define NPASS 2
#define K2T 1024                     // K2 block size
#define K2U 8                        // flat entries per thread per tile
#define NCH 4096                     // chunks per pass (guarded)
#define NBIN 2304                    // bin->run table, 32 flats/bin
#define WIN 2048                     // K3 LDS window (8 KB)
#define LDS_SEGS_FB 4096

typedef int            vint4    __attribute__((ext_vector_type(4)));
typedef float          vfloat4  __attribute__((ext_vector_type(4)));
typedef unsigned short vushort8 __attribute__((ext_vector_type(8)));

// ---------------------------------------------------------------- K1
// Chunk-local 256-way bin; ushort-packed writeout + chunkInfo emission.
__global__ __launch_bounds__(THREADS) void k1_bin256(
    const int* __restrict__ ptrs, const int* __restrict__ csr,
    unsigned short* __restrict__ ptrB, unsigned short* __restrict__ csrB,
    unsigned short* __restrict__ offs, int2* __restrict__ chunkInfo, int shift)
{
    __shared__ int  hist[NB];
    __shared__ int  scanb[NB];
    __shared__ int  curs[NB];
    __shared__ int  sFirst;
    __shared__ int2 buf[EPB];                 // 32 KB

    const int tid = threadIdx.x;              // THREADS == NB == 256
    const long long cb = (long long)blockIdx.x * EPB;
    const long long base = cb + (long long)tid * PER_THREAD;

    const vint4* p4 = (const vint4*)(ptrs + base);
    const vint4* c4 = (const vint4*)(csr + base);
    int p[PER_THREAD], c[PER_THREAD];
#pragma unroll
    for (int k = 0; k < PER_THREAD / 4; ++k) {
        vint4 a = __builtin_nontemporal_load(p4 + k);
        vint4 b = __builtin_nontemporal_load(c4 + k);
        p[4 * k + 0] = a.x; p[4 * k + 1] = a.y; p[4 * k + 2] = a.z; p[4 * k + 3] = a.w;
        c[4 * k + 0] = b.x; c[4 * k + 1] = b.y; c[4 * k + 2] = b.z; c[4 * k + 3] = b.w;
    }

    if (tid == 0) sFirst = c[0];              // csr[cb] (sorted: chunk min)
    hist[tid] = 0;
    __syncthreads();
#pragma unroll
    for (int j = 0; j < PER_THREAD; ++j)
        atomicAdd(&hist[p[j] >> shift], 1);
    __syncthreads();

    const int hv = hist[tid];
    scanb[tid] = hv;
    __syncthreads();
    for (int d = 1; d < NB; d <<= 1) {
        int u = (tid >= d) ? scanb[tid - d] : 0;
        __syncthreads();
        scanb[tid] += u;
        __syncthreads();
    }
    const int excl = scanb[tid] - hv;         // exclusive prefix
    curs[tid] = excl;
    offs[(size_t)blockIdx.x * NB + tid] = (unsigned short)excl;
    __syncthreads();

#pragma unroll
    for (int j = 0; j < PER_THREAD; ++j) {
        const int b = p[j] >> shift;
        const int pos = atomicAdd(&curs[b], 1);
        buf[pos] = make_int2(p[j], c[j]);
    }
    __syncthreads();

    // pair-packed ushort writeout (4B nt stores)
    const int first = sFirst;
    unsigned int* pOut = (unsigned int*)(ptrB + cb);
    unsigned int* cOut = (unsigned int*)(csrB + cb);
    for (int i = tid * 2; i < EPB; i += 2 * THREADS) {
        int2 e0 = buf[i];
        int2 e1 = buf[i + 1];
        unsigned int pp = (unsigned int)(e0.x & (SLICE - 1)) |
                          ((unsigned int)(e1.x & (SLICE - 1)) << 16);
        unsigned int cc = (unsigned int)(unsigned short)(e0.y - first) |
                          ((unsigned int)(unsigned short)(e1.y - first) << 16);
        __builtin_nontemporal_store(pp, pOut + (i >> 1));
        __builtin_nontemporal_store(cc, cOut + (i >> 1));
    }
    if (tid == THREADS - 1)
        chunkInfo[blockIdx.x] = make_int2(first, c[PER_THREAD - 1] - first);
}

// ---------------------------------------------------------------- kT
// offs [chunksP][NB] ushort -> offsT [NB][chunksP] (unchanged, proven).
__global__ __launch_bounds__(THREADS) void kT_transpose(
    const unsigned short* __restrict__ in, unsigned short* __restrict__ out,
    int chunksP)
{
    __shared__ unsigned short t[64][65];
    const int c  = threadIdx.x & 63;
    const int r4 = threadIdx.x >> 6;
    const int j0 = blockIdx.x * 64;
    const int b0 = blockIdx.y * 64;
    for (int rr = r4; rr < 64; rr += 4)
        t[rr][c] = in[(size_t)(j0 + rr) * NB + b0 + c];
    __syncthreads();
    for (int rr = r4; rr < 64; rr += 4)
        out[(size_t)(b0 + rr) * chunksP + j0 + c] = t[c][rr];
}

// ---------------------------------------------------------------- K2
// Block b: x slice (128 KiB) + packed run table (pfx<<13|srs) + 32-flat-bin
// lookup table in LDS. Lane-major flat iteration; branchless parallel-probe
// lookup (proven R12). ptrB is now ushort (15-bit slice-local index).
__global__ __launch_bounds__(K2T) void k2_ldsgather(
    const float* __restrict__ x, const unsigned short* __restrict__ ptrB,
    const unsigned short* __restrict__ offsT, float* __restrict__ v,
    int chunksP)
{
    __shared__ float sl[SLICE];               // 128 KiB
    __shared__ int   packed[NCH + 8];         // 16 KiB (pfx<<13 | srs) + sentinels
    __shared__ int   table[NBIN];             // 9 KiB (scan scratch, then bin->run)
    __shared__ int   sTot;

    const int tid = threadIdx.x;
    const int b = blockIdx.x;
    const bool lastB = (b == NB - 1);

    // stage slice (read exactly once per pass)
    const vfloat4* xs = (const vfloat4*)(x + (size_t)b * SLICE);
    vfloat4* ls = (vfloat4*)sl;
    for (int i = tid; i < SLICE / 4; i += K2T)
        ls[i] = __builtin_nontemporal_load(xs + i);

    // this thread's 4 runs: starts + lengths (kept in registers)
    const unsigned short* rowS = offsT + (size_t)b * chunksP;
    const unsigned short* rowE = offsT + (size_t)(b + 1) * chunksP;
    const int q0 = tid * 4;
    const int s0 = rowS[q0], s1 = rowS[q0 + 1], s2 = rowS[q0 + 2], s3 = rowS[q0 + 3];
    const int e0 = lastB ? EPB : (int)rowE[q0];
    const int e1 = lastB ? EPB : (int)rowE[q0 + 1];
    const int e2 = lastB ? EPB : (int)rowE[q0 + 2];
    const int e3 = lastB ? EPB : (int)rowE[q0 + 3];
    const int l0 = e0 - s0, l1 = e1 - s1, l2 = e2 - s2, l3 = e3 - s3;
    const int lsum = l0 + l1 + l2 + l3;

    // 1024-wide Hillis-Steele scan of per-thread sums (table as scratch)
    table[tid] = lsum;
    __syncthreads();
    for (int d = 1; d < K2T; d <<= 1) {
        int u = (tid >= d) ? table[tid - d] : 0;
        __syncthreads();
        table[tid] += u;
        __syncthreads();
    }
    const int texcl = table[tid] - lsum;
    if (tid == K2T - 1) sTot = texcl + lsum;
    __syncthreads();                          // table reads done; sTot visible
    const int T = sTot;

    const int p0 = texcl, p1 = texcl + l0, p2 = p1 + l1, p3 = p2 + l2, p4 = texcl + lsum;

    packed[q0]     = (p0 << 13) | s0;
    packed[q0 + 1] = (p1 << 13) | s1;
    packed[q0 + 2] = (p2 << 13) | s2;
    packed[q0 + 3] = (p3 << 13) | s3;
    if (tid < 8) packed[NCH + tid] = (T << 13);   // sentinels

    {
        const int pa[5] = { p0, p1, p2, p3, p4 };
#pragma unroll
        for (int q = 0; q < 4; ++q) {
            int b0_ = (pa[q] + 31) >> 5;
            int b1_ = (pa[q + 1] + 31) >> 5;
            if (b0_ > NBIN) b0_ = NBIN;
            if (b1_ > NBIN) b1_ = NBIN;
            for (int bb = b0_; bb < b1_; ++bb) table[bb] = q0 + q;
        }
    }
    __syncthreads();

    for (int fb = 0; fb < T; fb += K2T * K2U) {
        int gi[K2U];
#pragma unroll
        for (int k = 0; k < K2U; ++k) {
            const int f = fb + k * K2T + tid;
            const bool valid = (f < T);
            const int fe = valid ? f : 0;
            int bb = fe >> 5;
            if (bb >= NBIN) bb = NBIN - 1;
            const int j0j = table[bb];
            const int pk0 = packed[j0j];
            const int pk1 = packed[j0j + 1];
            const int pk2 = packed[j0j + 2];
            const int pk3 = packed[j0j + 3];
            const int pk4 = packed[j0j + 4];
            const int pk5 = packed[j0j + 5];
            const int i1 = ((pk1 >> 13) <= fe);
            const int i2 = ((pk2 >> 13) <= fe);
            const int i3 = ((pk3 >> 13) <= fe);
            const int i4 = ((pk4 >> 13) <= fe);
            const int i5 = ((pk5 >> 13) <= fe);
            int jp = j0j + i1 + i2 + i3 + i4 + i5;
            int sel = pk0;
            sel = i1 ? pk1 : sel;
            sel = i2 ? pk2 : sel;
            sel = i3 ? pk3 : sel;
            sel = i4 ? pk4 : sel;
            sel = i5 ? pk5 : sel;
            if (i5) {                         // rare tail
                while ((packed[jp + 1] >> 13) <= fe) ++jp;
                sel = packed[jp];
            }
            const int g = jp * EPB + (sel & 0x1FFF) + (fe - (sel >> 13));
            gi[k] = valid ? g : -1;
        }
        int pi[K2U];
#pragma unroll
        for (int k = 0; k < K2U; ++k)
            pi[k] = (gi[k] >= 0) ? (int)ptrB[gi[k]] : 0;
        float va[K2U];
#pragma unroll
        for (int k = 0; k < K2U; ++k)
            va[k] = sl[pi[k]];
#pragma unroll
        for (int k = 0; k < K2U; ++k)
            if (gi[k] >= 0) v[gi[k]] = va[k];
    }
}

// ---------------------------------------------------------------- K3
// 2 chunks per block (j, j+gridDim). All 12 loads for BOTH chunks issued up
// front -> chunk B latency hides under chunk A's zero/atomic/flush phases.
// csrB is rel-ushort; chunkInfo = (segBase, span). Interior segs exclusively
// owned (csr sorted) -> nt store; rel==0 / rel==span -> atomicAdd.
__device__ __forceinline__ void k3_process(
    float* __restrict__ win, int tid,
    vushort8 r0, vushort8 r1, vfloat4 f0, vfloat4 f1, vfloat4 f2, vfloat4 f3,
    int sb, int span, float* __restrict__ out)
{
#define K3REL(k) ((k) < 8 ? (int)r0[(k) & 7] : (int)r1[(k) & 7])
#define K3VAL(k) ((k) < 4 ? f0[(k) & 3] : (k) < 8 ? f1[(k) & 3] : (k) < 12 ? f2[(k) & 3] : f3[(k) & 3])
    for (int wb = 0; wb <= span; wb += WIN) {
        const int we = (wb + WIN - 1 < span) ? (wb + WIN - 1) : span;
        const int wlen = we - wb + 1;
        for (int s = tid; s < wlen; s += THREADS) win[s] = 0.0f;
        __syncthreads();
#pragma unroll
        for (int k = 0; k < PER_THREAD; ++k) {
            const int r = K3REL(k);
            if (r >= wb && r <= we) atomicAdd(&win[r - wb], K3VAL(k));
        }
        __syncthreads();
        for (int s = tid; s < wlen; s += THREADS) {
            const int r = wb + s;
            const float val = win[s];
            if (r == 0 || r == span) { if (val != 0.0f) atomicAdd(out + sb + r, val); }
            else __builtin_nontemporal_store(val, out + sb + r);
        }
        __syncthreads();
    }
#undef K3REL
#undef K3VAL
}

__global__ __launch_bounds__(THREADS) void k3_combine(
    const int2* __restrict__ chunkInfo, const unsigned short* __restrict__ csrB,
    const float* __restrict__ v, float* __restrict__ out)
{
    __shared__ float win[WIN];
    const int tid = threadIdx.x;

    const int j0 = blockIdx.x;
    const int j1 = blockIdx.x + gridDim.x;
    const long long cb0 = (long long)j0 * EPB;
    const long long cb1 = (long long)j1 * EPB;

    // issue ALL loads up front (independent; B's latency hidden under A)
    const vushort8* ca = (const vushort8*)(csrB + cb0) + tid * 2;
    const vfloat4*  va = (const vfloat4*)(v + cb0) + tid * 4;
    const vushort8* cbp = (const vushort8*)(csrB + cb1) + tid * 2;
    const vfloat4*  vb = (const vfloat4*)(v + cb1) + tid * 4;

    vushort8 ra0 = __builtin_nontemporal_load(ca);
    vushort8 ra1 = __builtin_nontemporal_load(ca + 1);
    vfloat4  fa0 = __builtin_nontemporal_load(va);
    vfloat4  fa1 = __builtin_nontemporal_load(va + 1);
    vfloat4  fa2 = __builtin_nontemporal_load(va + 2);
    vfloat4  fa3 = __builtin_nontemporal_load(va + 3);
    vushort8 rb0 = __builtin_nontemporal_load(cbp);
    vushort8 rb1 = __builtin_nontemporal_load(cbp + 1);
    vfloat4  fb0 = __builtin_nontemporal_load(vb);
    vfloat4  fb1 = __builtin_nontemporal_load(vb + 1);
    vfloat4  fb2 = __builtin_nontemporal_load(vb + 2);
    vfloat4  fb3 = __builtin_nontemporal_load(vb + 3);

    const int2 info0 = chunkInfo[j0];
    const int2 info1 = chunkInfo[j1];

    k3_process(win, tid, ra0, ra1, fa0, fa1, fa2, fa3, info0.x, info0.y, out);
    k3_process(win, tid, rb0, rb1, fb0, fb1, fb2, fb3, info1.x, info1.y, out);
}

// ------------------------------------------------- Fallback (= proven R3)
__global__ __launch_bounds__(THREADS) void fallback_segsum(
    const float* __restrict__ x, const int* __restrict__ ptrs,
    const int* __restrict__ csr, float* __restrict__ out)
{
    __shared__ float seg[LDS_SEGS_FB];
    const int tid = threadIdx.x;
    const long long blk_base = (long long)blockIdx.x * EPB;
    const long long base = blk_base + (long long)tid * PER_THREAD;

    const int seg_base = csr[blk_base];
    const int seg_last = csr[blk_base + EPB - 1];
    const int span = seg_last - seg_base + 1;

    for (int s = tid; s < LDS_SEGS_FB; s += THREADS) seg[s] = 0.0f;

    const vint4* p4 = (const vint4*)(ptrs + base);
    const vint4* c4 = (const vint4*)(csr + base);
    int p[PER_THREAD], c[PER_THREAD];
#pragma unroll
    for (int k = 0; k < PER_THREAD / 4; ++k) {
        vint4 a = __builtin_nontemporal_load(p4 + k);
        vint4 b = __builtin_nontemporal_load(c4 + k);
        p[4 * k + 0] = a.x; p[4 * k + 1] = a.y; p[4 * k + 2] = a.z; p[4 * k + 3] = a.w;
        c[4 * k + 0] = b.x; c[4 * k + 1] = b.y; c[4 * k + 2] = b.z; c[4 * k + 3] = b.w;
    }
    float v[PER_THREAD];
#pragma unroll
    for (int j = 0; j < PER_THREAD; ++j) v[j] = x[p[j]];
    __syncthreads();

    if (span <= LDS_SEGS_FB) {
        float acc = v[0]; int cur = c[0];
#pragma unroll
        for (int j = 1; j < PER_THREAD; ++j) {
            if (c[j] == cur) acc += v[j];
            else { atomicAdd(&seg[cur - seg_base], acc); cur = c[j]; acc = v[j]; }
        }
        atomicAdd(&seg[cur - seg_base], acc);
        __syncthreads();
        for (int s = tid; s < span; s += THREADS) {
            const int g = seg_base + s;
            const float val = seg[s];
            if (s == 0 || g == seg_last) { if (val != 0.0f) atomicAdd(out + g, val); }
            else __builtin_nontemporal_store(val, out + g);
        }
    } else {
        float acc = v[0]; int cur = c[0];
#pragma unroll
        for (int j = 1; j < PER_THREAD; ++j) {
            if (c[j] == cur) acc += v[j];
            else { atomicAdd(out + cur, acc); cur = c[j]; acc = v[j]; }
        }
        atomicAdd(out + cur, acc);
    }
}

extern "C" void kernel_launch(void* const* d_in, const int* in_sizes, int n_in,
                              void* d_out, int out_size, void* d_ws, size_t ws_size,
                              hipStream_t stream) {
    const float* x    = (const float*)d_in[0];
    const int*   ptrs = (const int*)d_in[1];
    const int*   csr  = (const int*)d_in[2];
    float*       out  = (float*)d_out;

    const long long nnz = in_sizes[1];            // 33,554,432
    const int x_size = in_sizes[0];               // 8,388,608

    (void)hipMemsetAsync(d_out, 0, (size_t)out_size * sizeof(float), stream);

    const long long nnzP = nnz / NPASS;           // 16,777,216
    const long long chunksP = nnzP / EPB;         // 4,096
    const bool ok_shapes =
        (nnz % ((long long)NPASS * EPB) == 0) &&
        (x_size % NB == 0) && (x_size / NB == SLICE) &&
        (chunksP == NCH) &&                        // K2 tables + K3 grid halving
        (chunksP % 64 == 0) &&                     // transpose tiling
        nnzP < (long long)INT_MAX / 2;

    const size_t a16Bytes  = ((size_t)nnzP * 2 + 255) & ~(size_t)255;       // ptrB16/csrB16
    const size_t vBytes    = ((size_t)nnzP * 4 + 255) & ~(size_t)255;
    const size_t offsBytes = ((size_t)chunksP * NB * 2 + 255) & ~(size_t)255;
    const size_t infoBytes = ((size_t)chunksP * 8 + 255) & ~(size_t)255;
    const size_t need      = 2 * a16Bytes + vBytes + 2 * offsBytes + infoBytes + 512; // ~132 MB

    if (ok_shapes && ws_size >= need) {
        char* w = (char*)d_ws;
        unsigned short* ptrB16 = (unsigned short*)w;
        unsigned short* csrB16 = (unsigned short*)(w + a16Bytes);
        float*          vbuf   = (float*)(w + 2 * a16Bytes);
        unsigned short* offs   = (unsigned short*)(w + 2 * a16Bytes + vBytes);
        unsigned short* offsT  = (unsigned short*)(w + 2 * a16Bytes + vBytes + offsBytes);
        int2*           cInfo  = (int2*)(w + 2 * a16Bytes + vBytes + 2 * offsBytes);
        const int shift = __builtin_ctz((unsigned)SLICE);   // 15

        for (int g = 0; g < NPASS; ++g) {
            const int* pg = ptrs + (long long)g * nnzP;
            const int* cg = csr  + (long long)g * nnzP;
            k1_bin256   <<<(int)chunksP, THREADS, 0, stream>>>(pg, cg, ptrB16, csrB16, offs, cInfo, shift);
            kT_transpose<<<dim3((int)(chunksP / 64), NB / 64), THREADS, 0, stream>>>(offs, offsT, (int)chunksP);
            k2_ldsgather<<<NB, K2T, 0, stream>>>(x, ptrB16, offsT, vbuf, (int)chunksP);
            k3_combine  <<<(int)(chunksP / 2), THREADS, 0, stream>>>(cInfo, csrB16, vbuf, out);
        }
    } else {
        fallback_segsum<<<(int)(nnz / EPB), THREADS, 0, stream>>>(x, ptrs, csr, out);
    }
}